// Round 4
// baseline (355.228 us; speedup 1.0000x reference)
//
#include <hip/hip_runtime.h>

typedef __bf16 bf16_t;
typedef __bf16 bf16x4 __attribute__((ext_vector_type(4)));
typedef __bf16 bf16x8 __attribute__((ext_vector_type(8)));
typedef float  floatx4 __attribute__((ext_vector_type(4)));

#define MFMA16(a, b, c) __builtin_amdgcn_mfma_f32_16x16x32_bf16((a), (b), (c), 0, 0, 0)

// fp32 element offsets inside d_out
#define ADJ_OFF  2097152
#define MU_OFF   2162688
#define LV_OFF   4259840

#define TWO_LOG2E 2.8853900817779268f

// tanh(x) given argE2 = 2*log2(e)*x:  tanh = 1 - 2/(2^argE2 + 1).
// Saturates correctly at +-inf (exp2->inf/0 -> +-1), no NaN.
__device__ __forceinline__ float fast_tanh2(float argE2) {
    float e = __builtin_amdgcn_exp2f(argE2);
    return 1.0f - 2.0f * __builtin_amdgcn_rcpf(e + 1.0f);
}

__device__ __forceinline__ bf16x8 cvt8(const float* p) {
    const floatx4 a = *(const floatx4*)p;
    const floatx4 b = *(const floatx4*)(p + 4);
    bf16x8 r;
#pragma unroll
    for (int j = 0; j < 4; j++) { r[j] = (bf16_t)a[j]; r[4 + j] = (bf16_t)b[j]; }
    return r;
}

// ---------------------------------------------------------------------------
// K0: prep.  Blocks 0-47: LDS-tile transpose-cast of the 3 encoder weights.
// Block 48: wef = f32(Wemb*2log2e) + pack Wg1 -> wg1pk (bf16, fragment
// layout, so k_gcn does 4 vector loads instead of 32 scalar+cvt).
// Block 49: bef = f32(bemb*2log2e).  f32 tables kill the 2 bf16->f32 cvts
// per tanh element in k_gcn phase 1 (round-1 evidence: VALUBusy 40->24).
// ---------------------------------------------------------------------------
__global__ __launch_bounds__(256) void k_prep(
    const float* __restrict__ We, const float* __restrict__ Wm,
    const float* __restrict__ Wl, const float* __restrict__ Wemb,
    const float* __restrict__ bemb, const float* __restrict__ Wg1,
    bf16_t* __restrict__ Wt, float* __restrict__ wef,
    float* __restrict__ bef, bf16_t* __restrict__ wg1pk) {
    __shared__ float tile[64][65];
    const int b = blockIdx.x, tid = threadIdx.x;
    if (b < 48) {
        const int m = b >> 4, t6 = b & 15;
        const int K0 = (t6 >> 2) << 6, N0 = (t6 & 3) << 6;
        const float* src = (m == 0) ? We : ((m == 1) ? Wm : Wl);
#pragma unroll
        for (int p = 0; p < 16; p++) {
            const int idx = p * 256 + tid;
            tile[idx >> 6][idx & 63] = src[(K0 + (idx >> 6)) * 256 + N0 + (idx & 63)];
        }
        __syncthreads();
        bf16_t* dst = Wt + m * 65536;
#pragma unroll
        for (int p = 0; p < 16; p++) {
            const int idx = p * 256 + tid;
            const int nn = idx >> 6, kk = idx & 63;
            dst[(N0 + nn) * 256 + K0 + kk] = (bf16_t)tile[kk][nn];
        }
    } else if (b == 48) {
#pragma unroll 4
        for (int p = 0; p < 64; p++)
            wef[p * 256 + tid] = TWO_LOG2E * Wemb[p * 256 + tid];
        if (wg1pk) {
            // wg1pk[((ks*2+te)*16+n)*32 + q*8 + j] = Wg1[(ks*32+q*8+j)*32+te*16+n]
#pragma unroll
            for (int idx = tid; idx < 2048; idx += 256) {
                const int jj = idx & 7, qq = (idx >> 3) & 3, nn = (idx >> 5) & 15;
                const int te = (idx >> 9) & 1, ks = (idx >> 10) & 1;
                wg1pk[idx] = (bf16_t)Wg1[(ks * 32 + qq * 8 + jj) * 32 + te * 16 + nn];
            }
        }
    } else {
#pragma unroll 4
        for (int p = 0; p < 64; p++)
            bef[p * 256 + tid] = TWO_LOG2E * bemb[p * 256 + tid];
    }
}

// ---------------------------------------------------------------------------
// K1: merged degrees + M build (replaces k_deg+k_mkM; no atomics, no
// colc/rsO scratch, one less launch).  Block j, thread t: loop the whole
// gp column-slice (coalesced, L2-resident 256 KB) counting col-t nonzeros;
// capture row-j's value + ballot for the row count on the jp==j iteration.
// ---------------------------------------------------------------------------
__global__ __launch_bounds__(256) void k_mkM(
    const float* __restrict__ gp, const int* __restrict__ iterp,
    bf16_t* __restrict__ Mb) {
    __shared__ unsigned long long mk[4];
    const int j = blockIdx.x, t = threadIdx.x;
    const bool thr = (*iterp) > 50;
    int cnt = 0;
    float gjt = 0.0f;
#pragma unroll 4
    for (int jp = 0; jp < 256; jp++) {
        float g = 1.0f / (1.0f + expf(-gp[jp * 256 + t]));
        if (t == jp) g = 1.0f;
        if (thr && !(g > 0.1f)) g = 0.0f;
        const bool nz = (g != 0.0f);
        cnt += nz ? 1 : 0;
        if (jp == j) {                       // wave-uniform condition
            gjt = g;
            const unsigned long long bal = __ballot(nz);
            if ((t & 63) == 0) mk[t >> 6] = bal;
        }
    }
    __syncthreads();
    const int rc = (int)(__popcll(mk[0]) + __popcll(mk[1]) +
                         __popcll(mk[2]) + __popcll(mk[3]));
    const float rso = rsqrtf((float)(rc < 1 ? 1 : rc));
    const float rsi = rsqrtf((float)(cnt < 1 ? 1 : cnt));
    Mb[t * 256 + j] = (bf16_t)(gjt * rso * rsi);
}

// ---------------------------------------------------------------------------
// K3: fused encoder+heads v2.  512 blocks x 512 thr, 16-row bands.
// Stage X band -> LDS bf16 once (no redundant global A loads).
// Phase A: H = relu(Xs@We+be) -> Hs LDS.  Phase B: mu/lv = Hs@{Wm,Wl}+b.
// LDS: 2 x 16x264 bf16 = 16.9 KB.
// ---------------------------------------------------------------------------
__global__ __launch_bounds__(512) void k_ench(
    const float* __restrict__ X, const bf16_t* __restrict__ Wt,
    const float* __restrict__ benc, const float* __restrict__ bmu,
    const float* __restrict__ blv,
    float* __restrict__ MuOut, float* __restrict__ LvOut) {
    __shared__ __align__(16) bf16_t Xs[16 * 264];
    __shared__ __align__(16) bf16_t Hs[16 * 264];
    const bf16_t* Bte = Wt;
    const bf16_t* Btm = Wt + 65536;
    const bf16_t* Btl = Wt + 131072;
    const int tid = threadIdx.x;
    const int r0 = blockIdx.x * 16;
    const int w = tid >> 6;
    const int lane = tid & 63;
    const int n = lane & 15, q = lane >> 4;
    const int cw = w * 32;
    const floatx4 z4 = {0.f, 0.f, 0.f, 0.f};

    // stage X band [16 x 256] fp32 -> bf16 LDS (8 elems/thread, coalesced)
    {
        const int e0 = tid * 8;
        const int row = e0 >> 8, col = e0 & 255;
        *(bf16x8*)(Xs + row * 264 + col) = cvt8(X + (r0 + row) * 256 + col);
    }
    __syncthreads();

    // ---- phase A ----
    floatx4 ah[2];
#pragma unroll
    for (int tc = 0; tc < 2; tc++) ah[tc] = z4;
#pragma unroll 2
    for (int k0 = 0; k0 < 256; k0 += 32) {
        const bf16x8 a = *(const bf16x8*)(Xs + n * 264 + k0 + q * 8);
        bf16x8 b[2];
#pragma unroll
        for (int tc = 0; tc < 2; tc++)
            b[tc] = *(const bf16x8*)(Bte + (cw + tc * 16 + n) * 256 + k0 + q * 8);
#pragma unroll
        for (int tc = 0; tc < 2; tc++) ah[tc] = MFMA16(a, b[tc], ah[tc]);
    }
#pragma unroll
    for (int tc = 0; tc < 2; tc++) {
        const int col = cw + tc * 16 + n;
        const float bv = benc[col];
#pragma unroll
        for (int r = 0; r < 4; r++)
            Hs[(q * 4 + r) * 264 + col] = (bf16_t)fmaxf(ah[tc][r] + bv, 0.0f);
    }
    __syncthreads();

    // ---- phase B ----
    floatx4 am[2], al[2];
#pragma unroll
    for (int tc = 0; tc < 2; tc++) { am[tc] = z4; al[tc] = z4; }
#pragma unroll 2
    for (int k0 = 0; k0 < 256; k0 += 32) {
        const bf16x8 a = *(const bf16x8*)(Hs + n * 264 + k0 + q * 8);
        bf16x8 bm_[2], bl_[2];
#pragma unroll
        for (int tc = 0; tc < 2; tc++) {
            bm_[tc] = *(const bf16x8*)(Btm + (cw + tc * 16 + n) * 256 + k0 + q * 8);
            bl_[tc] = *(const bf16x8*)(Btl + (cw + tc * 16 + n) * 256 + k0 + q * 8);
        }
#pragma unroll
        for (int tc = 0; tc < 2; tc++) {
            am[tc] = MFMA16(a, bm_[tc], am[tc]);
            al[tc] = MFMA16(a, bl_[tc], al[tc]);
        }
    }
#pragma unroll
    for (int tc = 0; tc < 2; tc++) {
        const int col = cw + tc * 16 + n;
        const float bmv = bmu[col], blvv = blv[col];
#pragma unroll
        for (int r = 0; r < 4; r++) {
            const int row = r0 + q * 4 + r;
            MuOut[row * 256 + col] = am[tc][r] + bmv;
            LvOut[row * 256 + col] = al[tc][r] + blvv;
        }
    }
}

// ---------------------------------------------------------------------------
// K4: fused GCN v8.  4096 blocks x 512 thr, 2 batch rows/block.
// Deltas vs the 115.7us v7 (round 3), ONLY in the VALU-dominant phase 1:
//  (a) f32 we/be tables: kills the 2 bf16->f32 cvts per tanh element
//      (round-1 evidence: VALUBusy 40->24 with this change, spoiled only
//      by spill; now 48 VGPR + 128 cap -> +32 VGPR table fragments fit).
//  (b) Wg1 preload from prepacked bf16 fragments (4 vector loads) instead
//      of 32 scalar loads + 32 cvts per thread (wg1pk==nullptr falls back).
// Spill invariant: WRITE_SIZE must stay 8192 KB.
// ---------------------------------------------------------------------------
__global__ __launch_bounds__(512, 4) void k_gcn(
    const float* __restrict__ Mu, const float* __restrict__ Lv,
    const float* __restrict__ Eps, const float* __restrict__ wef,
    const float* __restrict__ bef, const float* __restrict__ Wg1,
    const bf16_t* __restrict__ wg1pk, const float* __restrict__ bg1,
    const float* __restrict__ Wg2, const bf16_t* __restrict__ Mb,
    float* __restrict__ Vout) {
    __shared__ __align__(16) bf16_t smem[64 * 256];
    __shared__ float zs[512];
    const int tid = threadIdx.x;
    const int lane = tid & 63;
    const int w = tid >> 6;                 // wave 0..7
    const int n = lane & 15, q = lane >> 4;
    const int bg = blockIdx.x;              // batch pair
    const floatx4 z4 = {0.f, 0.f, 0.f, 0.f};

    // stage z (coalesced fp32 reads)
    {
        const int gi = bg * 512 + tid;
        zs[tid] = fmaf(Eps[gi], __expf(0.5f * Lv[gi]), Mu[gi]);
    }

    // preload W_g1 B-fragments
    bf16x8 wg1f[2][2];
    if (wg1pk) {
#pragma unroll
        for (int ks = 0; ks < 2; ks++)
#pragma unroll
            for (int te = 0; te < 2; te++)
                wg1f[ks][te] = *(const bf16x8*)(wg1pk +
                    ((ks * 2 + te) * 16 + n) * 32 + q * 8);
    } else {
#pragma unroll
        for (int ks = 0; ks < 2; ks++)
#pragma unroll
            for (int te = 0; te < 2; te++)
#pragma unroll
                for (int j = 0; j < 8; j++)
                    wg1f[ks][te][j] =
                        (bf16_t)Wg1[(ks * 32 + q * 8 + j) * 32 + te * 16 + n];
    }
    __syncthreads();

    // ---- phase 1: wave w -> j-tiles {2w, 2w+1}, each for bl 0 and 1 ----
#pragma unroll
    for (int jt2 = 0; jt2 < 2; jt2++) {
        const int j0 = (w * 2 + jt2) * 16;
        const int jA = j0 + n;
        // f32 table fragments loaded ONCE per j-tile, reused for both rows
        const float* wp = wef + jA * 64;
        const float* bp = bef + jA * 64;
        const floatx4 w0a = *(const floatx4*)(wp + q * 8);
        const floatx4 w0b = *(const floatx4*)(wp + q * 8 + 4);
        const floatx4 w1a = *(const floatx4*)(wp + 32 + q * 8);
        const floatx4 w1b = *(const floatx4*)(wp + 32 + q * 8 + 4);
        const floatx4 b0a = *(const floatx4*)(bp + q * 8);
        const floatx4 b0b = *(const floatx4*)(bp + q * 8 + 4);
        const floatx4 b1a = *(const floatx4*)(bp + 32 + q * 8);
        const floatx4 b1b = *(const floatx4*)(bp + 32 + q * 8 + 4);
        const int j8a = (j0 >> 3) + (q >> 1);
        const int jlo = (q & 1) * 4;
        const int sw = ((j8a ^ (n & 7)) << 3) + jlo;
#pragma unroll
        for (int bl = 0; bl < 2; bl++) {
            const float zv = zs[bl * 256 + jA];   // 2log2e folded into tables
            bf16x8 a0, a1;
#pragma unroll
            for (int j = 0; j < 4; j++) {
                a0[j]     = (bf16_t)fast_tanh2(fmaf(zv, w0a[j], b0a[j]));
                a0[4 + j] = (bf16_t)fast_tanh2(fmaf(zv, w0b[j], b0b[j]));
                a1[j]     = (bf16_t)fast_tanh2(fmaf(zv, w1a[j], b1a[j]));
                a1[4 + j] = (bf16_t)fast_tanh2(fmaf(zv, w1b[j], b1b[j]));
            }
            floatx4 c0 = z4, c1 = z4;
            c0 = MFMA16(a0, wg1f[0][0], c0);
            c0 = MFMA16(a1, wg1f[1][0], c0);
            c1 = MFMA16(a0, wg1f[0][1], c1);
            c1 = MFMA16(a1, wg1f[1][1], c1);
            bf16x4 s0, s1;
#pragma unroll
            for (int r = 0; r < 4; r++) { s0[r] = (bf16_t)c0[r]; s1[r] = (bf16_t)c1[r]; }
            *(bf16x4*)(smem + (bl * 32 + n) * 256 + sw) = s0;        // e = n
            *(bf16x4*)(smem + (bl * 32 + 16 + n) * 256 + sw) = s1;   // e = 16+n
        }
    }
    __syncthreads();

    // ---- phase 2: T1 = M @ Q (wave w: i in [w*32,w*32+32), c in [0,64)) ----
    const int i0 = w * 32;
    floatx4 acc[2][4];
#pragma unroll
    for (int ti = 0; ti < 2; ti++)
#pragma unroll
        for (int tc = 0; tc < 4; tc++) acc[ti][tc] = z4;
#pragma unroll 2
    for (int k0 = 0; k0 < 256; k0 += 32) {
        const int k8 = k0 >> 3;
        bf16x8 a[2], b[4];
#pragma unroll
        for (int ti = 0; ti < 2; ti++)
            a[ti] = *(const bf16x8*)(Mb + (i0 + ti * 16 + n) * 256 + k0 + q * 8);
#pragma unroll
        for (int tc = 0; tc < 4; tc++)
            b[tc] = *(const bf16x8*)(smem + (tc * 16 + n) * 256 +
                                     (((k8 + q) ^ (n & 7)) << 3));
        __builtin_amdgcn_s_setprio(1);
#pragma unroll
        for (int ti = 0; ti < 2; ti++)
#pragma unroll
            for (int tc = 0; tc < 4; tc++)
                acc[ti][tc] = MFMA16(a[ti], b[tc], acc[ti][tc]);
        __builtin_amdgcn_s_setprio(0);
    }

    // ---- epilogue: in-register relu+Wg2 contraction + reduce-scatter ----
    // lane covers e = n (tc 0,2) and e = 16+n (tc 1,3); bl = tc>>1.
    const float w2a = Wg2[n],      w2b = Wg2[16 + n];
    const float b1a = bg1[n],      b1b = bg1[16 + n];
    float v16[16];   // k = bl*8 + ti*4 + r
#pragma unroll
    for (int ti = 0; ti < 2; ti++)
#pragma unroll
        for (int r = 0; r < 4; r++) {
            v16[ti * 4 + r] =
                fmaxf(acc[ti][0][r] + b1a, 0.0f) * w2a +
                fmaxf(acc[ti][1][r] + b1b, 0.0f) * w2b;
            v16[8 + ti * 4 + r] =
                fmaxf(acc[ti][2][r] + b1a, 0.0f) * w2a +
                fmaxf(acc[ti][3][r] + b1b, 0.0f) * w2b;
        }
    // reduce-scatter over lane bits 0..3 (the 16 n-lanes); lane ends with k=n.
    const bool h0 = (lane & 1), h1_ = (lane & 2), h2 = (lane & 4), h3 = (lane & 8);
    float v8[8];
#pragma unroll
    for (int p = 0; p < 8; p++) {
        const float keep = h0 ? v16[2 * p + 1] : v16[2 * p];
        const float send = h0 ? v16[2 * p] : v16[2 * p + 1];
        v8[p] = keep + __shfl_xor(send, 1, 64);
    }
    float v4_[4];
#pragma unroll
    for (int p = 0; p < 4; p++) {
        const float keep = h1_ ? v8[2 * p + 1] : v8[2 * p];
        const float send = h1_ ? v8[2 * p] : v8[2 * p + 1];
        v4_[p] = keep + __shfl_xor(send, 2, 64);
    }
    float v2_[2];
#pragma unroll
    for (int p = 0; p < 2; p++) {
        const float keep = h2 ? v4_[2 * p + 1] : v4_[2 * p];
        const float send = h2 ? v4_[2 * p] : v4_[2 * p + 1];
        v2_[p] = keep + __shfl_xor(send, 4, 64);
    }
    {
        const float keep = h3 ? v2_[1] : v2_[0];
        const float send = h3 ? v2_[0] : v2_[1];
        const float vfin = keep + __shfl_xor(send, 8, 64);
        // lane holds k = n: r = n&3, ti = (n>>2)&1, bl = n>>3
        const int i_out = i0 + ((n >> 2) & 1) * 16 + q * 4 + (n & 3);
        Vout[bg * 512 + (n >> 3) * 256 + i_out] = vfin;
    }
}

// ---------------------------------------------------------------------------
// K5: x_hat = V @ M^T + b_g2, in place.  512 blocks, 16-row bands, 8 waves.
// ---------------------------------------------------------------------------
__global__ __launch_bounds__(512) void k_out(
    float* __restrict__ VX, const bf16_t* __restrict__ Mb,
    const float* __restrict__ bg2) {
    __shared__ __align__(16) bf16_t va[16 * 264];
    const int tid = threadIdx.x;
    const int lane = tid & 63;
    const int w = tid >> 6;                 // wave 0..7 -> col group
    const int n = lane & 15, q = lane >> 4;
    const int r0 = blockIdx.x * 16;

#pragma unroll
    for (int p = 0; p < 2; p++) {
        const int i4 = p * 512 + tid;
        const int row = i4 >> 6, c4 = (i4 & 63) * 4;
        const floatx4 v = *(const floatx4*)(VX + (r0 + row) * 256 + c4);
        bf16x4 s;
#pragma unroll
        for (int r = 0; r < 4; r++) s[r] = (bf16_t)v[r];
        *(bf16x4*)(va + row * 264 + c4) = s;
    }
    __syncthreads();

    const int cw = w * 32;
    const floatx4 z4 = {0.f, 0.f, 0.f, 0.f};
    floatx4 acc[2];
    acc[0] = z4; acc[1] = z4;
#pragma unroll 2
    for (int k0 = 0; k0 < 256; k0 += 32) {
        const bf16x8 a = *(const bf16x8*)(va + n * 264 + k0 + q * 8);
        bf16x8 b[2];
#pragma unroll
        for (int tc = 0; tc < 2; tc++)
            b[tc] = *(const bf16x8*)(Mb + (cw + tc * 16 + n) * 256 + k0 + q * 8);
#pragma unroll
        for (int tc = 0; tc < 2; tc++) acc[tc] = MFMA16(a, b[tc], acc[tc]);
    }
    const float bv = bg2[0];
#pragma unroll
    for (int tc = 0; tc < 2; tc++) {
        const int col = cw + tc * 16 + n;
#pragma unroll
        for (int r = 0; r < 4; r++)
            VX[(r0 + q * 4 + r) * 256 + col] = acc[tc][r] + bv;
    }
}

// ---------------------------------------------------------------------------
// K6: restore the real adjacency (fp32) — runs LAST.
// ---------------------------------------------------------------------------
__global__ __launch_bounds__(256) void k_adj(
    const float* __restrict__ gp, const int* __restrict__ iterp,
    float* __restrict__ adjOut) {
    const int o = blockIdx.x * 256 + threadIdx.x;  // o = j*256 + i
    const int j = o >> 8, i = o & 255;
    float g = 1.0f / (1.0f + expf(-gp[o]));
    if (i == j) g = 1.0f;
    if ((*iterp) > 50 && !(g > 0.1f)) g = 0.0f;
    adjOut[o] = g;
}

// ---------------------------------------------------------------------------
extern "C" void kernel_launch(void* const* d_in, const int* in_sizes, int n_in,
                              void* d_out, int out_size, void* d_ws, size_t ws_size,
                              hipStream_t stream) {
    const float* x    = (const float*)d_in[0];
    const float* eps  = (const float*)d_in[1];
    const float* Wenc = (const float*)d_in[2];
    const float* benc = (const float*)d_in[3];
    const float* Wmu  = (const float*)d_in[4];
    const float* bmu  = (const float*)d_in[5];
    const float* Wlv  = (const float*)d_in[6];
    const float* blv  = (const float*)d_in[7];
    const float* gp   = (const float*)d_in[8];
    const float* Wemb = (const float*)d_in[9];
    const float* bemb = (const float*)d_in[10];
    const float* Wg1  = (const float*)d_in[11];
    const float* bg1  = (const float*)d_in[12];
    const float* Wg2  = (const float*)d_in[13];
    const float* bg2  = (const float*)d_in[14];
    const int*   itr  = (const int*)d_in[15];
    (void)in_sizes; (void)n_in; (void)out_size;

    float* xhat = (float*)d_out;             // [8192,256] fp32
    float* adjO = xhat + ADJ_OFF;            // [256,256]  fp32
    float* muo  = xhat + MU_OFF;             // [8192,256] fp32
    float* lvo  = xhat + LV_OFF;             // [8192,256] fp32

    // Scratch carved from OUTPUT slots:
    //  adj slot (256 KB): Mb [0,128K) | wef f32 [128K,192K) | bef f32
    //  [192K,256K).  Wt bf16 (384 KB) at xhat byte 4 MB: dead after k_ench
    //  (k_gcn overwrites xhat later — stream-serial, no hazard).
    //  wg1pk (4 KB, bf16 Wg1 fragments) lives in d_ws (guarded: nullptr
    //  fallback to scalar preload if no workspace).
    char* adjB = (char*)adjO;
    bf16_t* Mb  = (bf16_t*)adjB;
    float*  wef = (float*)(adjB + 131072);
    float*  bef = (float*)(adjB + 196608);
    bf16_t* Wt  = (bf16_t*)((char*)d_out + 4194304);
    bf16_t* wg1pk = (d_ws != nullptr && ws_size >= 4096) ? (bf16_t*)d_ws : nullptr;

    k_prep<<<dim3(50), dim3(256), 0, stream>>>(Wenc, Wmu, Wlv, Wemb, bemb, Wg1,
                                               Wt, wef, bef, wg1pk);
    k_mkM <<<dim3(256), dim3(256), 0, stream>>>(gp, itr, Mb);
    k_ench<<<dim3(512), dim3(512), 0, stream>>>(x, Wt, benc, bmu, blv, muo, lvo);
    k_gcn <<<dim3(4096), dim3(512), 0, stream>>>(muo, lvo, eps, wef, bef,
                                                 Wg1, wg1pk, bg1, Wg2, Mb, xhat);
    k_out <<<dim3(512), dim3(512), 0, stream>>>(xhat, Mb, bg2);
    k_adj <<<dim3(256), dim3(256), 0, stream>>>(gp, itr, adjO);
}

// Round 5
// 246.016 us; speedup vs baseline: 1.4439x; 1.4439x over previous
//
#include <hip/hip_runtime.h>

typedef __bf16 bf16_t;
typedef __bf16 bf16x4 __attribute__((ext_vector_type(4)));
typedef __bf16 bf16x8 __attribute__((ext_vector_type(8)));
typedef float  floatx4 __attribute__((ext_vector_type(4)));

#define MFMA16(a, b, c) __builtin_amdgcn_mfma_f32_16x16x32_bf16((a), (b), (c), 0, 0, 0)

// fp32 element offsets inside d_out
#define ADJ_OFF  2097152
#define MU_OFF   2162688
#define LV_OFF   4259840

#define TWO_LOG2E 2.8853900817779268f

// tanh(x) given argE2 = 2*log2(e)*x:  tanh = 1 - 2/(2^argE2 + 1).
// Saturates correctly at +-inf (exp2->inf/0 -> +-1), no NaN.
__device__ __forceinline__ float fast_tanh2(float argE2) {
    float e = __builtin_amdgcn_exp2f(argE2);
    return 1.0f - 2.0f * __builtin_amdgcn_rcpf(e + 1.0f);
}

__device__ __forceinline__ bf16x8 cvt8(const float* p) {
    const floatx4 a = *(const floatx4*)p;
    const floatx4 b = *(const floatx4*)(p + 4);
    bf16x8 r;
#pragma unroll
    for (int j = 0; j < 4; j++) { r[j] = (bf16_t)a[j]; r[4 + j] = (bf16_t)b[j]; }
    return r;
}

// ---------------------------------------------------------------------------
// K0: prep.  Blocks 0-47: LDS-tile transpose-cast of the 3 encoder weights.
// Block 48: wepack = bf16(Wemb * 2log2e).  Block 49: bepack = bf16(bemb *
// 2log2e) + zero colc.  (2log2e folded so tanh uses raw v_exp_f32.)
// (round-4 lesson: f32 tables made the compiler rematerialize loads under
//  the reg cap -> slower despite fewer cvts.  bf16 tables are the good
//  equilibrium; do not change.)
// ---------------------------------------------------------------------------
__global__ __launch_bounds__(256) void k_prep(
    const float* __restrict__ We, const float* __restrict__ Wm,
    const float* __restrict__ Wl, const float* __restrict__ Wemb,
    const float* __restrict__ bemb, bf16_t* __restrict__ Wt,
    bf16_t* __restrict__ wepack, bf16_t* __restrict__ bepack,
    int* __restrict__ colc) {
    __shared__ float tile[64][65];
    const int b = blockIdx.x, tid = threadIdx.x;
    if (b < 48) {
        const int m = b >> 4, t6 = b & 15;
        const int K0 = (t6 >> 2) << 6, N0 = (t6 & 3) << 6;
        const float* src = (m == 0) ? We : ((m == 1) ? Wm : Wl);
#pragma unroll
        for (int p = 0; p < 16; p++) {
            const int idx = p * 256 + tid;
            tile[idx >> 6][idx & 63] = src[(K0 + (idx >> 6)) * 256 + N0 + (idx & 63)];
        }
        __syncthreads();
        bf16_t* dst = Wt + m * 65536;
#pragma unroll
        for (int p = 0; p < 16; p++) {
            const int idx = p * 256 + tid;
            const int nn = idx >> 6, kk = idx & 63;
            dst[(N0 + nn) * 256 + K0 + kk] = (bf16_t)tile[kk][nn];
        }
    } else if (b == 48) {
#pragma unroll 4
        for (int p = 0; p < 64; p++)
            wepack[p * 256 + tid] = (bf16_t)(TWO_LOG2E * Wemb[p * 256 + tid]);
    } else {
        colc[tid] = 0;
#pragma unroll 4
        for (int p = 0; p < 64; p++)
            bepack[p * 256 + tid] = (bf16_t)(TWO_LOG2E * bemb[p * 256 + tid]);
    }
}

// ---------------------------------------------------------------------------
// K1: degrees, 256 blocks (block j = adjacency row j).
// (round-4 lesson: the merged-loop variant regressed ~80us — likely I$
//  thrash from 256 unrolled expf bodies at 1 block/CU.  Keep split.)
// ---------------------------------------------------------------------------
__global__ __launch_bounds__(256) void k_deg(
    const float* __restrict__ gp, const int* __restrict__ iterp,
    int* __restrict__ colc, float* __restrict__ rsO) {
    __shared__ unsigned long long mk[4];
    const int j = blockIdx.x, t = threadIdx.x;
    const bool thr = (*iterp) > 50;
    float g = 1.0f / (1.0f + expf(-gp[j * 256 + t]));
    if (t == j) g = 1.0f;
    if (thr && !(g > 0.1f)) g = 0.0f;
    const bool nz = (g != 0.0f);
    const unsigned long long bal = __ballot(nz);
    if ((t & 63) == 0) mk[t >> 6] = bal;
    if (nz) atomicAdd(&colc[t], 1);
    __syncthreads();
    if (t == 0) {
        const int rc = (int)(__popcll(mk[0]) + __popcll(mk[1]) +
                             __popcll(mk[2]) + __popcll(mk[3]));
        rsO[j] = rsqrtf((float)(rc < 1 ? 1 : rc));
    }
}

// ---------------------------------------------------------------------------
// K2: M bf16.  Block j, thread t: M[t][j] = adj[j][t]*rsO[j]*rsI[t].
// ---------------------------------------------------------------------------
__global__ __launch_bounds__(256) void k_mkM(
    const float* __restrict__ gp, const int* __restrict__ iterp,
    const int* __restrict__ colc, const float* __restrict__ rsO,
    bf16_t* __restrict__ Mb) {
    const int j = blockIdx.x, t = threadIdx.x;
    const int ci = colc[t];
    const float rsi = rsqrtf((float)(ci < 1 ? 1 : ci));
    float g = 1.0f / (1.0f + expf(-gp[j * 256 + t]));
    if (t == j) g = 1.0f;
    if ((*iterp) > 50 && !(g > 0.1f)) g = 0.0f;
    Mb[t * 256 + j] = (bf16_t)(g * rsO[j] * rsi);
}

// ---------------------------------------------------------------------------
// K3: fused encoder+heads v2.  512 blocks x 512 thr, 16-row bands.
// Stage X band -> LDS bf16 once (no redundant global A loads).
// Phase A: H = relu(Xs@We+be) -> Hs LDS.  Phase B: mu/lv = Hs@{Wm,Wl}+b.
// LDS: 2 x 16x264 bf16 = 16.9 KB.
// ---------------------------------------------------------------------------
__global__ __launch_bounds__(512) void k_ench(
    const float* __restrict__ X, const bf16_t* __restrict__ Wt,
    const float* __restrict__ benc, const float* __restrict__ bmu,
    const float* __restrict__ blv,
    float* __restrict__ MuOut, float* __restrict__ LvOut) {
    __shared__ __align__(16) bf16_t Xs[16 * 264];
    __shared__ __align__(16) bf16_t Hs[16 * 264];
    const bf16_t* Bte = Wt;
    const bf16_t* Btm = Wt + 65536;
    const bf16_t* Btl = Wt + 131072;
    const int tid = threadIdx.x;
    const int r0 = blockIdx.x * 16;
    const int w = tid >> 6;
    const int lane = tid & 63;
    const int n = lane & 15, q = lane >> 4;
    const int cw = w * 32;
    const floatx4 z4 = {0.f, 0.f, 0.f, 0.f};

    // stage X band [16 x 256] fp32 -> bf16 LDS (8 elems/thread, coalesced)
    {
        const int e0 = tid * 8;
        const int row = e0 >> 8, col = e0 & 255;
        *(bf16x8*)(Xs + row * 264 + col) = cvt8(X + (r0 + row) * 256 + col);
    }
    __syncthreads();

    // ---- phase A ----
    floatx4 ah[2];
#pragma unroll
    for (int tc = 0; tc < 2; tc++) ah[tc] = z4;
#pragma unroll 2
    for (int k0 = 0; k0 < 256; k0 += 32) {
        const bf16x8 a = *(const bf16x8*)(Xs + n * 264 + k0 + q * 8);
        bf16x8 b[2];
#pragma unroll
        for (int tc = 0; tc < 2; tc++)
            b[tc] = *(const bf16x8*)(Bte + (cw + tc * 16 + n) * 256 + k0 + q * 8);
#pragma unroll
        for (int tc = 0; tc < 2; tc++) ah[tc] = MFMA16(a, b[tc], ah[tc]);
    }
#pragma unroll
    for (int tc = 0; tc < 2; tc++) {
        const int col = cw + tc * 16 + n;
        const float bv = benc[col];
#pragma unroll
        for (int r = 0; r < 4; r++)
            Hs[(q * 4 + r) * 264 + col] = (bf16_t)fmaxf(ah[tc][r] + bv, 0.0f);
    }
    __syncthreads();

    // ---- phase B ----
    floatx4 am[2], al[2];
#pragma unroll
    for (int tc = 0; tc < 2; tc++) { am[tc] = z4; al[tc] = z4; }
#pragma unroll 2
    for (int k0 = 0; k0 < 256; k0 += 32) {
        const bf16x8 a = *(const bf16x8*)(Hs + n * 264 + k0 + q * 8);
        bf16x8 bm_[2], bl_[2];
#pragma unroll
        for (int tc = 0; tc < 2; tc++) {
            bm_[tc] = *(const bf16x8*)(Btm + (cw + tc * 16 + n) * 256 + k0 + q * 8);
            bl_[tc] = *(const bf16x8*)(Btl + (cw + tc * 16 + n) * 256 + k0 + q * 8);
        }
#pragma unroll
        for (int tc = 0; tc < 2; tc++) {
            am[tc] = MFMA16(a, bm_[tc], am[tc]);
            al[tc] = MFMA16(a, bl_[tc], al[tc]);
        }
    }
#pragma unroll
    for (int tc = 0; tc < 2; tc++) {
        const int col = cw + tc * 16 + n;
        const float bmv = bmu[col], blvv = blv[col];
#pragma unroll
        for (int r = 0; r < 4; r++) {
            const int row = r0 + q * 4 + r;
            MuOut[row * 256 + col] = am[tc][r] + bmv;
            LvOut[row * 256 + col] = al[tc][r] + blvv;
        }
    }
}

// ---------------------------------------------------------------------------
// K4: fused GCN v9.  4096 blocks x 512 thr, 2 batch rows/block.
// = the 115.7us round-3 build (bf16 tables, jt2 table reuse, (512,4) cap,
//   setprio) with ONE delta: phase-2 k-loop FULLY unrolled (was unroll 2).
//   8 iters x (2 Mb loads + 4 LDS reads + 8 MFMA) now one scheduling
//   region; ~80 free regs under the 128 cap let the compiler hoist loads
//   across iterations itself (round-3 evidence: headroom, not hand
//   pipelining, is what wins).  Spill invariant: WRITE_SIZE == 8192 KB.
// ---------------------------------------------------------------------------
__global__ __launch_bounds__(512, 4) void k_gcn(
    const float* __restrict__ Mu, const float* __restrict__ Lv,
    const float* __restrict__ Eps, const bf16_t* __restrict__ wepack,
    const bf16_t* __restrict__ bepack, const float* __restrict__ Wg1,
    const float* __restrict__ bg1, const float* __restrict__ Wg2,
    const bf16_t* __restrict__ Mb, float* __restrict__ Vout) {
    __shared__ __align__(16) bf16_t smem[64 * 256];
    __shared__ float zs[512];
    const int tid = threadIdx.x;
    const int lane = tid & 63;
    const int w = tid >> 6;                 // wave 0..7
    const int n = lane & 15, q = lane >> 4;
    const int bg = blockIdx.x;              // batch pair
    const floatx4 z4 = {0.f, 0.f, 0.f, 0.f};

    // stage z (coalesced fp32 reads)
    {
        const int gi = bg * 512 + tid;
        zs[tid] = fmaf(Eps[gi], __expf(0.5f * Lv[gi]), Mu[gi]);
    }

    // preload W_g1 B-fragments
    bf16x8 wg1f[2][2];
#pragma unroll
    for (int ks = 0; ks < 2; ks++)
#pragma unroll
        for (int te = 0; te < 2; te++)
#pragma unroll
            for (int j = 0; j < 8; j++)
                wg1f[ks][te][j] = (bf16_t)Wg1[(ks * 32 + q * 8 + j) * 32 + te * 16 + n];
    __syncthreads();

    // ---- phase 1: wave w -> j-tiles {2w, 2w+1}, each for bl 0 and 1 ----
#pragma unroll
    for (int jt2 = 0; jt2 < 2; jt2++) {
        const int j0 = (w * 2 + jt2) * 16;
        const int jA = j0 + n;
        // table fragments loaded ONCE per j-tile, reused for both batch rows
        const bf16x8 we0 = *(const bf16x8*)(wepack + jA * 64 + q * 8);
        const bf16x8 we1 = *(const bf16x8*)(wepack + jA * 64 + 32 + q * 8);
        const bf16x8 be0 = *(const bf16x8*)(bepack + jA * 64 + q * 8);
        const bf16x8 be1 = *(const bf16x8*)(bepack + jA * 64 + 32 + q * 8);
        const int j8a = (j0 >> 3) + (q >> 1);
        const int jlo = (q & 1) * 4;
        const int sw = ((j8a ^ (n & 7)) << 3) + jlo;
#pragma unroll
        for (int bl = 0; bl < 2; bl++) {
            const float zv = zs[bl * 256 + jA];   // 2log2e folded into packs
            bf16x8 a0, a1;
#pragma unroll
            for (int j = 0; j < 8; j++) {
                a0[j] = (bf16_t)fast_tanh2(fmaf(zv, (float)we0[j], (float)be0[j]));
                a1[j] = (bf16_t)fast_tanh2(fmaf(zv, (float)we1[j], (float)be1[j]));
            }
            floatx4 c0 = z4, c1 = z4;
            c0 = MFMA16(a0, wg1f[0][0], c0);
            c0 = MFMA16(a1, wg1f[1][0], c0);
            c1 = MFMA16(a0, wg1f[0][1], c1);
            c1 = MFMA16(a1, wg1f[1][1], c1);
            bf16x4 s0, s1;
#pragma unroll
            for (int r = 0; r < 4; r++) { s0[r] = (bf16_t)c0[r]; s1[r] = (bf16_t)c1[r]; }
            *(bf16x4*)(smem + (bl * 32 + n) * 256 + sw) = s0;        // e = n
            *(bf16x4*)(smem + (bl * 32 + 16 + n) * 256 + sw) = s1;   // e = 16+n
        }
    }
    __syncthreads();

    // ---- phase 2: T1 = M @ Q (wave w: i in [w*32,w*32+32), c in [0,64)) ----
    const int i0 = w * 32;
    floatx4 acc[2][4];
#pragma unroll
    for (int ti = 0; ti < 2; ti++)
#pragma unroll
        for (int tc = 0; tc < 4; tc++) acc[ti][tc] = z4;
#pragma unroll
    for (int k0 = 0; k0 < 256; k0 += 32) {
        const int k8 = k0 >> 3;
        bf16x8 a[2], b[4];
#pragma unroll
        for (int ti = 0; ti < 2; ti++)
            a[ti] = *(const bf16x8*)(Mb + (i0 + ti * 16 + n) * 256 + k0 + q * 8);
#pragma unroll
        for (int tc = 0; tc < 4; tc++)
            b[tc] = *(const bf16x8*)(smem + (tc * 16 + n) * 256 +
                                     (((k8 + q) ^ (n & 7)) << 3));
        __builtin_amdgcn_s_setprio(1);
#pragma unroll
        for (int ti = 0; ti < 2; ti++)
#pragma unroll
            for (int tc = 0; tc < 4; tc++)
                acc[ti][tc] = MFMA16(a[ti], b[tc], acc[ti][tc]);
        __builtin_amdgcn_s_setprio(0);
    }

    // ---- epilogue: in-register relu+Wg2 contraction + reduce-scatter ----
    // lane covers e = n (tc 0,2) and e = 16+n (tc 1,3); bl = tc>>1.
    const float w2a = Wg2[n],      w2b = Wg2[16 + n];
    const float b1a = bg1[n],      b1b = bg1[16 + n];
    float v16[16];   // k = bl*8 + ti*4 + r
#pragma unroll
    for (int ti = 0; ti < 2; ti++)
#pragma unroll
        for (int r = 0; r < 4; r++) {
            v16[ti * 4 + r] =
                fmaxf(acc[ti][0][r] + b1a, 0.0f) * w2a +
                fmaxf(acc[ti][1][r] + b1b, 0.0f) * w2b;
            v16[8 + ti * 4 + r] =
                fmaxf(acc[ti][2][r] + b1a, 0.0f) * w2a +
                fmaxf(acc[ti][3][r] + b1b, 0.0f) * w2b;
        }
    // reduce-scatter over lane bits 0..3 (the 16 n-lanes); lane ends with k=n.
    const bool h0 = (lane & 1), h1_ = (lane & 2), h2 = (lane & 4), h3 = (lane & 8);
    float v8[8];
#pragma unroll
    for (int p = 0; p < 8; p++) {
        const float keep = h0 ? v16[2 * p + 1] : v16[2 * p];
        const float send = h0 ? v16[2 * p] : v16[2 * p + 1];
        v8[p] = keep + __shfl_xor(send, 1, 64);
    }
    float v4_[4];
#pragma unroll
    for (int p = 0; p < 4; p++) {
        const float keep = h1_ ? v8[2 * p + 1] : v8[2 * p];
        const float send = h1_ ? v8[2 * p] : v8[2 * p + 1];
        v4_[p] = keep + __shfl_xor(send, 2, 64);
    }
    float v2_[2];
#pragma unroll
    for (int p = 0; p < 2; p++) {
        const float keep = h2 ? v4_[2 * p + 1] : v4_[2 * p];
        const float send = h2 ? v4_[2 * p] : v4_[2 * p + 1];
        v2_[p] = keep + __shfl_xor(send, 4, 64);
    }
    {
        const float keep = h3 ? v2_[1] : v2_[0];
        const float send = h3 ? v2_[0] : v2_[1];
        const float vfin = keep + __shfl_xor(send, 8, 64);
        // lane holds k = n: r = n&3, ti = (n>>2)&1, bl = n>>3
        const int i_out = i0 + ((n >> 2) & 1) * 16 + q * 4 + (n & 3);
        Vout[bg * 512 + (n >> 3) * 256 + i_out] = vfin;
    }
}

// ---------------------------------------------------------------------------
// K5: x_hat = V @ M^T + b_g2, in place.  512 blocks, 16-row bands, 8 waves.
// ---------------------------------------------------------------------------
__global__ __launch_bounds__(512) void k_out(
    float* __restrict__ VX, const bf16_t* __restrict__ Mb,
    const float* __restrict__ bg2) {
    __shared__ __align__(16) bf16_t va[16 * 264];
    const int tid = threadIdx.x;
    const int lane = tid & 63;
    const int w = tid >> 6;                 // wave 0..7 -> col group
    const int n = lane & 15, q = lane >> 4;
    const int r0 = blockIdx.x * 16;

#pragma unroll
    for (int p = 0; p < 2; p++) {
        const int i4 = p * 512 + tid;
        const int row = i4 >> 6, c4 = (i4 & 63) * 4;
        const floatx4 v = *(const floatx4*)(VX + (r0 + row) * 256 + c4);
        bf16x4 s;
#pragma unroll
        for (int r = 0; r < 4; r++) s[r] = (bf16_t)v[r];
        *(bf16x4*)(va + row * 264 + c4) = s;
    }
    __syncthreads();

    const int cw = w * 32;
    const floatx4 z4 = {0.f, 0.f, 0.f, 0.f};
    floatx4 acc[2];
    acc[0] = z4; acc[1] = z4;
#pragma unroll 2
    for (int k0 = 0; k0 < 256; k0 += 32) {
        const bf16x8 a = *(const bf16x8*)(va + n * 264 + k0 + q * 8);
        bf16x8 b[2];
#pragma unroll
        for (int tc = 0; tc < 2; tc++)
            b[tc] = *(const bf16x8*)(Mb + (cw + tc * 16 + n) * 256 + k0 + q * 8);
#pragma unroll
        for (int tc = 0; tc < 2; tc++) acc[tc] = MFMA16(a, b[tc], acc[tc]);
    }
    const float bv = bg2[0];
#pragma unroll
    for (int tc = 0; tc < 2; tc++) {
        const int col = cw + tc * 16 + n;
#pragma unroll
        for (int r = 0; r < 4; r++)
            VX[(r0 + q * 4 + r) * 256 + col] = acc[tc][r] + bv;
    }
}

// ---------------------------------------------------------------------------
// K6: restore the real adjacency (fp32) — runs LAST.
// ---------------------------------------------------------------------------
__global__ __launch_bounds__(256) void k_adj(
    const float* __restrict__ gp, const int* __restrict__ iterp,
    float* __restrict__ adjOut) {
    const int o = blockIdx.x * 256 + threadIdx.x;  // o = j*256 + i
    const int j = o >> 8, i = o & 255;
    float g = 1.0f / (1.0f + expf(-gp[o]));
    if (i == j) g = 1.0f;
    if ((*iterp) > 50 && !(g > 0.1f)) g = 0.0f;
    adjOut[o] = g;
}

// ---------------------------------------------------------------------------
extern "C" void kernel_launch(void* const* d_in, const int* in_sizes, int n_in,
                              void* d_out, int out_size, void* d_ws, size_t ws_size,
                              hipStream_t stream) {
    const float* x    = (const float*)d_in[0];
    const float* eps  = (const float*)d_in[1];
    const float* Wenc = (const float*)d_in[2];
    const float* benc = (const float*)d_in[3];
    const float* Wmu  = (const float*)d_in[4];
    const float* bmu  = (const float*)d_in[5];
    const float* Wlv  = (const float*)d_in[6];
    const float* blv  = (const float*)d_in[7];
    const float* gp   = (const float*)d_in[8];
    const float* Wemb = (const float*)d_in[9];
    const float* bemb = (const float*)d_in[10];
    const float* Wg1  = (const float*)d_in[11];
    const float* bg1  = (const float*)d_in[12];
    const float* Wg2  = (const float*)d_in[13];
    const float* bg2  = (const float*)d_in[14];
    const int*   itr  = (const int*)d_in[15];
    (void)d_ws; (void)ws_size; (void)in_sizes; (void)n_in; (void)out_size;

    float* xhat = (float*)d_out;             // [8192,256] fp32
    float* adjO = xhat + ADJ_OFF;            // [256,256]  fp32
    float* muo  = xhat + MU_OFF;             // [8192,256] fp32
    float* lvo  = xhat + LV_OFF;             // [8192,256] fp32

    // Scratch carved from OUTPUT slots (zero d_ws footprint):
    //  adj slot (256 KB): Mb [0,128K) | wepack [128K,160K) | bepack(2log2e)
    //  [160K,192K) | colc int[256] [192K,193K) | rsO [193K,194K).
    //  Wt bf16 (384 KB) at xhat byte 4 MB: dead after k_ench.
    char* adjB = (char*)adjO;
    bf16_t* Mb     = (bf16_t*)adjB;
    bf16_t* wepack = (bf16_t*)(adjB + 131072);
    bf16_t* bepack = (bf16_t*)(adjB + 163840);
    int*    colc   = (int*)(adjB + 196608);
    float*  rsO    = (float*)(adjB + 197632);
    bf16_t* Wt     = (bf16_t*)((char*)d_out + 4194304);

    k_prep<<<dim3(50), dim3(256), 0, stream>>>(Wenc, Wmu, Wlv, Wemb, bemb,
                                               Wt, wepack, bepack, colc);
    k_deg <<<dim3(256), dim3(256), 0, stream>>>(gp, itr, colc, rsO);
    k_mkM <<<dim3(256), dim3(256), 0, stream>>>(gp, itr, colc, rsO, Mb);
    k_ench<<<dim3(512), dim3(512), 0, stream>>>(x, Wt, benc, bmu, blv, muo, lvo);
    k_gcn <<<dim3(4096), dim3(512), 0, stream>>>(muo, lvo, eps, wepack, bepack,
                                                 Wg1, bg1, Wg2, Mb, xhat);
    k_out <<<dim3(512), dim3(512), 0, stream>>>(xhat, Mb, bg2);
    k_adj <<<dim3(256), dim3(256), 0, stream>>>(gp, itr, adjO);
}

// Round 7
// 212.506 us; speedup vs baseline: 1.6716x; 1.1577x over previous
//
#include <hip/hip_runtime.h>

typedef __bf16 bf16_t;
typedef __bf16 bf16x4 __attribute__((ext_vector_type(4)));
typedef __bf16 bf16x8 __attribute__((ext_vector_type(8)));
typedef float  floatx4 __attribute__((ext_vector_type(4)));

#define MFMA16(a, b, c) __builtin_amdgcn_mfma_f32_16x16x32_bf16((a), (b), (c), 0, 0, 0)

// fp32 element offsets inside d_out
#define ADJ_OFF  2097152
#define MU_OFF   2162688
#define LV_OFF   4259840

#define TWO_LOG2E 2.8853900817779268f

// tanh(x) given argE2 = 2*log2(e)*x:  tanh = 1 - 2/(2^argE2 + 1).
// Saturates correctly at +-inf (exp2->inf/0 -> +-1), no NaN.
__device__ __forceinline__ float fast_tanh2(float argE2) {
    float e = __builtin_amdgcn_exp2f(argE2);
    return 1.0f - 2.0f * __builtin_amdgcn_rcpf(e + 1.0f);
}

__device__ __forceinline__ bf16x8 cvt8(const float* p) {
    const floatx4 a = *(const floatx4*)p;
    const floatx4 b = *(const floatx4*)(p + 4);
    bf16x8 r;
#pragma unroll
    for (int j = 0; j < 4; j++) { r[j] = (bf16_t)a[j]; r[4 + j] = (bf16_t)b[j]; }
    return r;
}

// ---------------------------------------------------------------------------
// K0: prep.  Blocks 0-47: LDS-tile transpose-cast of the 3 encoder weights.
// Block 48: wepack = bf16(Wemb * 2log2e).  Block 49: bepack = bf16(bemb *
// 2log2e) + zero colc.  (2log2e folded so tanh uses raw v_exp_f32.)
// ---------------------------------------------------------------------------
__global__ __launch_bounds__(256) void k_prep(
    const float* __restrict__ We, const float* __restrict__ Wm,
    const float* __restrict__ Wl, const float* __restrict__ Wemb,
    const float* __restrict__ bemb, bf16_t* __restrict__ Wt,
    bf16_t* __restrict__ wepack, bf16_t* __restrict__ bepack,
    int* __restrict__ colc) {
    __shared__ float tile[64][65];
    const int b = blockIdx.x, tid = threadIdx.x;
    if (b < 48) {
        const int m = b >> 4, t6 = b & 15;
        const int K0 = (t6 >> 2) << 6, N0 = (t6 & 3) << 6;
        const float* src = (m == 0) ? We : ((m == 1) ? Wm : Wl);
#pragma unroll
        for (int p = 0; p < 16; p++) {
            const int idx = p * 256 + tid;
            tile[idx >> 6][idx & 63] = src[(K0 + (idx >> 6)) * 256 + N0 + (idx & 63)];
        }
        __syncthreads();
        bf16_t* dst = Wt + m * 65536;
#pragma unroll
        for (int p = 0; p < 16; p++) {
            const int idx = p * 256 + tid;
            const int nn = idx >> 6, kk = idx & 63;
            dst[(N0 + nn) * 256 + K0 + kk] = (bf16_t)tile[kk][nn];
        }
    } else if (b == 48) {
#pragma unroll 4
        for (int p = 0; p < 64; p++)
            wepack[p * 256 + tid] = (bf16_t)(TWO_LOG2E * Wemb[p * 256 + tid]);
    } else {
        colc[tid] = 0;
#pragma unroll 4
        for (int p = 0; p < 64; p++)
            bepack[p * 256 + tid] = (bf16_t)(TWO_LOG2E * bemb[p * 256 + tid]);
    }
}

// ---------------------------------------------------------------------------
// K1: degrees, 256 blocks (block j = adjacency row j).
// ---------------------------------------------------------------------------
__global__ __launch_bounds__(256) void k_deg(
    const float* __restrict__ gp, const int* __restrict__ iterp,
    int* __restrict__ colc, float* __restrict__ rsO) {
    __shared__ unsigned long long mk[4];
    const int j = blockIdx.x, t = threadIdx.x;
    const bool thr = (*iterp) > 50;
    float g = 1.0f / (1.0f + expf(-gp[j * 256 + t]));
    if (t == j) g = 1.0f;
    if (thr && !(g > 0.1f)) g = 0.0f;
    const bool nz = (g != 0.0f);
    const unsigned long long bal = __ballot(nz);
    if ((t & 63) == 0) mk[t >> 6] = bal;
    if (nz) atomicAdd(&colc[t], 1);
    __syncthreads();
    if (t == 0) {
        const int rc = (int)(__popcll(mk[0]) + __popcll(mk[1]) +
                             __popcll(mk[2]) + __popcll(mk[3]));
        rsO[j] = rsqrtf((float)(rc < 1 ? 1 : rc));
    }
}

// ---------------------------------------------------------------------------
// K2: M bf16.  Block j, thread t: M[t][j] = adj[j][t]*rsO[j]*rsI[t].
// ---------------------------------------------------------------------------
__global__ __launch_bounds__(256) void k_mkM(
    const float* __restrict__ gp, const int* __restrict__ iterp,
    const int* __restrict__ colc, const float* __restrict__ rsO,
    bf16_t* __restrict__ Mb) {
    const int j = blockIdx.x, t = threadIdx.x;
    const int ci = colc[t];
    const float rsi = rsqrtf((float)(ci < 1 ? 1 : ci));
    float g = 1.0f / (1.0f + expf(-gp[j * 256 + t]));
    if (t == j) g = 1.0f;
    if ((*iterp) > 50 && !(g > 0.1f)) g = 0.0f;
    Mb[t * 256 + j] = (bf16_t)(g * rsO[j] * rsi);
}

// ---------------------------------------------------------------------------
// K3: fused encoder+heads v2.  512 blocks x 512 thr, 16-row bands.
// Stage X band -> LDS bf16 once (no redundant global A loads).
// Phase A: H = relu(Xs@We+be) -> Hs LDS.  Phase B: mu/lv = Hs@{Wm,Wl}+b.
// LDS: 2 x 16x264 bf16 = 16.9 KB.
// ---------------------------------------------------------------------------
__global__ __launch_bounds__(512) void k_ench(
    const float* __restrict__ X, const bf16_t* __restrict__ Wt,
    const float* __restrict__ benc, const float* __restrict__ bmu,
    const float* __restrict__ blv,
    float* __restrict__ MuOut, float* __restrict__ LvOut) {
    __shared__ __align__(16) bf16_t Xs[16 * 264];
    __shared__ __align__(16) bf16_t Hs[16 * 264];
    const bf16_t* Bte = Wt;
    const bf16_t* Btm = Wt + 65536;
    const bf16_t* Btl = Wt + 131072;
    const int tid = threadIdx.x;
    const int r0 = blockIdx.x * 16;
    const int w = tid >> 6;
    const int lane = tid & 63;
    const int n = lane & 15, q = lane >> 4;
    const int cw = w * 32;
    const floatx4 z4 = {0.f, 0.f, 0.f, 0.f};

    // stage X band [16 x 256] fp32 -> bf16 LDS (8 elems/thread, coalesced)
    {
        const int e0 = tid * 8;
        const int row = e0 >> 8, col = e0 & 255;
        *(bf16x8*)(Xs + row * 264 + col) = cvt8(X + (r0 + row) * 256 + col);
    }
    __syncthreads();

    // ---- phase A ----
    floatx4 ah[2];
#pragma unroll
    for (int tc = 0; tc < 2; tc++) ah[tc] = z4;
#pragma unroll 2
    for (int k0 = 0; k0 < 256; k0 += 32) {
        const bf16x8 a = *(const bf16x8*)(Xs + n * 264 + k0 + q * 8);
        bf16x8 b[2];
#pragma unroll
        for (int tc = 0; tc < 2; tc++)
            b[tc] = *(const bf16x8*)(Bte + (cw + tc * 16 + n) * 256 + k0 + q * 8);
#pragma unroll
        for (int tc = 0; tc < 2; tc++) ah[tc] = MFMA16(a, b[tc], ah[tc]);
    }
#pragma unroll
    for (int tc = 0; tc < 2; tc++) {
        const int col = cw + tc * 16 + n;
        const float bv = benc[col];
#pragma unroll
        for (int r = 0; r < 4; r++)
            Hs[(q * 4 + r) * 264 + col] = (bf16_t)fmaxf(ah[tc][r] + bv, 0.0f);
    }
    __syncthreads();

    // ---- phase B ----
    floatx4 am[2], al[2];
#pragma unroll
    for (int tc = 0; tc < 2; tc++) { am[tc] = z4; al[tc] = z4; }
#pragma unroll 2
    for (int k0 = 0; k0 < 256; k0 += 32) {
        const bf16x8 a = *(const bf16x8*)(Hs + n * 264 + k0 + q * 8);
        bf16x8 bm_[2], bl_[2];
#pragma unroll
        for (int tc = 0; tc < 2; tc++) {
            bm_[tc] = *(const bf16x8*)(Btm + (cw + tc * 16 + n) * 256 + k0 + q * 8);
            bl_[tc] = *(const bf16x8*)(Btl + (cw + tc * 16 + n) * 256 + k0 + q * 8);
        }
#pragma unroll
        for (int tc = 0; tc < 2; tc++) {
            am[tc] = MFMA16(a, bm_[tc], am[tc]);
            al[tc] = MFMA16(a, bl_[tc], al[tc]);
        }
    }
#pragma unroll
    for (int tc = 0; tc < 2; tc++) {
        const int col = cw + tc * 16 + n;
        const float bmv = bmu[col], blvv = blv[col];
#pragma unroll
        for (int r = 0; r < 4; r++) {
            const int row = r0 + q * 4 + r;
            MuOut[row * 256 + col] = am[tc][r] + bmv;
            LvOut[row * 256 + col] = al[tc][r] + blvv;
        }
    }
}

// ---------------------------------------------------------------------------
// K4: fused GCN v10b.  2048 blocks x 512 thr, FOUR batch rows/block.
// = round-6 BL=4 design with the epilogue typo fixed (u4 stage read
//   uninitialized u4[0] -> NaN).  Amortizes per-block fixed costs and
//   L2 re-reads (Mb 128K + tables 64K per block) over 2x work.
// Spill invariant: WRITE_SIZE == 8192 KB (if it rises, revert to BL=2).
// ---------------------------------------------------------------------------
__global__ __launch_bounds__(512, 4) void k_gcn(
    const float* __restrict__ Mu, const float* __restrict__ Lv,
    const float* __restrict__ Eps, const bf16_t* __restrict__ wepack,
    const bf16_t* __restrict__ bepack, const float* __restrict__ Wg1,
    const float* __restrict__ bg1, const float* __restrict__ Wg2,
    const bf16_t* __restrict__ Mb, float* __restrict__ Vout) {
    __shared__ __align__(16) bf16_t smem[128 * 256];   // 64 KB: 4 bl x 32 e
    __shared__ float zs[1024];
    const int tid = threadIdx.x;
    const int lane = tid & 63;
    const int w = tid >> 6;                 // wave 0..7
    const int n = lane & 15, q = lane >> 4;
    const int bg = blockIdx.x;              // batch quad
    const floatx4 z4 = {0.f, 0.f, 0.f, 0.f};

    // stage z for 4 rows (coalesced fp32 reads, 2 elems/thread)
    {
        const int gi = bg * 1024 + tid;
        zs[tid] = fmaf(Eps[gi], __expf(0.5f * Lv[gi]), Mu[gi]);
        const int gi2 = gi + 512;
        zs[tid + 512] = fmaf(Eps[gi2], __expf(0.5f * Lv[gi2]), Mu[gi2]);
    }

    // preload W_g1 B-fragments
    bf16x8 wg1f[2][2];
#pragma unroll
    for (int ks = 0; ks < 2; ks++)
#pragma unroll
        for (int te = 0; te < 2; te++)
#pragma unroll
            for (int j = 0; j < 8; j++)
                wg1f[ks][te][j] = (bf16_t)Wg1[(ks * 32 + q * 8 + j) * 32 + te * 16 + n];
    __syncthreads();

    // ---- phase 1: wave w -> j-tiles {2w, 2w+1}, each for bl 0..3 ----
#pragma unroll
    for (int jt2 = 0; jt2 < 2; jt2++) {
        const int j0 = (w * 2 + jt2) * 16;
        const int jA = j0 + n;
        // table fragments loaded ONCE per j-tile, reused for 4 batch rows
        const bf16x8 we0 = *(const bf16x8*)(wepack + jA * 64 + q * 8);
        const bf16x8 we1 = *(const bf16x8*)(wepack + jA * 64 + 32 + q * 8);
        const bf16x8 be0 = *(const bf16x8*)(bepack + jA * 64 + q * 8);
        const bf16x8 be1 = *(const bf16x8*)(bepack + jA * 64 + 32 + q * 8);
        const int j8a = (j0 >> 3) + (q >> 1);
        const int jlo = (q & 1) * 4;
        const int sw = ((j8a ^ (n & 7)) << 3) + jlo;
#pragma unroll
        for (int bl = 0; bl < 4; bl++) {
            const float zv = zs[bl * 256 + jA];   // 2log2e folded into packs
            bf16x8 a0, a1;
#pragma unroll
            for (int j = 0; j < 8; j++) {
                a0[j] = (bf16_t)fast_tanh2(fmaf(zv, (float)we0[j], (float)be0[j]));
                a1[j] = (bf16_t)fast_tanh2(fmaf(zv, (float)we1[j], (float)be1[j]));
            }
            floatx4 c0 = z4, c1 = z4;
            c0 = MFMA16(a0, wg1f[0][0], c0);
            c0 = MFMA16(a1, wg1f[1][0], c0);
            c1 = MFMA16(a0, wg1f[0][1], c1);
            c1 = MFMA16(a1, wg1f[1][1], c1);
            bf16x4 s0, s1;
#pragma unroll
            for (int r = 0; r < 4; r++) { s0[r] = (bf16_t)c0[r]; s1[r] = (bf16_t)c1[r]; }
            *(bf16x4*)(smem + (bl * 32 + n) * 256 + sw) = s0;        // e = n
            *(bf16x4*)(smem + (bl * 32 + 16 + n) * 256 + sw) = s1;   // e = 16+n
        }
    }
    __syncthreads();

    // ---- phase 2: T1 = M @ Q (wave w: i in [w*32,w*32+32), c in [0,128)) --
    const int i0 = w * 32;
    floatx4 acc[2][8];
#pragma unroll
    for (int ti = 0; ti < 2; ti++)
#pragma unroll
        for (int tc = 0; tc < 8; tc++) acc[ti][tc] = z4;
#pragma unroll
    for (int k0 = 0; k0 < 256; k0 += 32) {
        const int k8 = k0 >> 3;
        bf16x8 a[2], b[8];
#pragma unroll
        for (int ti = 0; ti < 2; ti++)
            a[ti] = *(const bf16x8*)(Mb + (i0 + ti * 16 + n) * 256 + k0 + q * 8);
#pragma unroll
        for (int tc = 0; tc < 8; tc++)
            b[tc] = *(const bf16x8*)(smem + (tc * 16 + n) * 256 +
                                     (((k8 + q) ^ (n & 7)) << 3));
        __builtin_amdgcn_s_setprio(1);
#pragma unroll
        for (int ti = 0; ti < 2; ti++)
#pragma unroll
            for (int tc = 0; tc < 8; tc++)
                acc[ti][tc] = MFMA16(a[ti], b[tc], acc[ti][tc]);
        __builtin_amdgcn_s_setprio(0);
    }

    // ---- epilogue: in-register relu+Wg2 contraction + reduce-scatter ----
    // lane covers e = n (tc even) and e = 16+n (tc odd); bl = tc>>1 in 0..3.
    const float w2a = Wg2[n],      w2b = Wg2[16 + n];
    const float b1a = bg1[n],      b1b = bg1[16 + n];
    float v32[32];   // k = bl*8 + ti*4 + r
#pragma unroll
    for (int bl = 0; bl < 4; bl++)
#pragma unroll
        for (int ti = 0; ti < 2; ti++)
#pragma unroll
            for (int r = 0; r < 4; r++)
                v32[bl * 8 + ti * 4 + r] =
                    fmaxf(acc[ti][2 * bl][r] + b1a, 0.0f) * w2a +
                    fmaxf(acc[ti][2 * bl + 1][r] + b1b, 0.0f) * w2b;
    // reduce-scatter over lane bits 0..3; lane ends with k = n and k = 16+n.
    const bool h0 = (lane & 1), h1_ = (lane & 2), h2 = (lane & 4), h3 = (lane & 8);
    float u16[16];
#pragma unroll
    for (int p = 0; p < 16; p++) {
        const float keep = h0 ? v32[2 * p + 1] : v32[2 * p];
        const float send = h0 ? v32[2 * p] : v32[2 * p + 1];
        u16[p] = keep + __shfl_xor(send, 1, 64);
    }
    float u8[8];
#pragma unroll
    for (int p = 0; p < 8; p++) {
        const float keep = h1_ ? u16[2 * p + 1] : u16[2 * p];
        const float send = h1_ ? u16[2 * p] : u16[2 * p + 1];
        u8[p] = keep + __shfl_xor(send, 2, 64);
    }
    float u4[4];
#pragma unroll
    for (int p = 0; p < 4; p++) {
        const float keep = h2 ? u8[2 * p + 1] : u8[2 * p];
        const float send = h2 ? u8[2 * p] : u8[2 * p + 1];
        u4[p] = keep + __shfl_xor(send, 4, 64);
    }
    float u2[2];
#pragma unroll
    for (int p = 0; p < 2; p++) {
        const float keep = h3 ? u4[2 * p + 1] : u4[2 * p];
        const float send = h3 ? u4[2 * p] : u4[2 * p + 1];
        u2[p] = keep + __shfl_xor(send, 8, 64);
    }
    {
        // lane holds k = 16*p + n: r = n&3, ti = (n>>2)&1, bl = p*2 + (n>>3)
        const int i_out = i0 + ((n >> 2) & 1) * 16 + q * 4 + (n & 3);
        const int blv = n >> 3;
        Vout[bg * 1024 + blv * 256 + i_out] = u2[0];
        Vout[bg * 1024 + (2 + blv) * 256 + i_out] = u2[1];
    }
}

// ---------------------------------------------------------------------------
// K5: x_hat = V @ M^T + b_g2, in place.  512 blocks, 16-row bands, 8 waves.
// ---------------------------------------------------------------------------
__global__ __launch_bounds__(512) void k_out(
    float* __restrict__ VX, const bf16_t* __restrict__ Mb,
    const float* __restrict__ bg2) {
    __shared__ __align__(16) bf16_t va[16 * 264];
    const int tid = threadIdx.x;
    const int lane = tid & 63;
    const int w = tid >> 6;                 // wave 0..7 -> col group
    const int n = lane & 15, q = lane >> 4;
    const int r0 = blockIdx.x * 16;

#pragma unroll
    for (int p = 0; p < 2; p++) {
        const int i4 = p * 512 + tid;
        const int row = i4 >> 6, c4 = (i4 & 63) * 4;
        const floatx4 v = *(const floatx4*)(VX + (r0 + row) * 256 + c4);
        bf16x4 s;
#pragma unroll
        for (int r = 0; r < 4; r++) s[r] = (bf16_t)v[r];
        *(bf16x4*)(va + row * 264 + c4) = s;
    }
    __syncthreads();

    const int cw = w * 32;
    const floatx4 z4 = {0.f, 0.f, 0.f, 0.f};
    floatx4 acc[2];
    acc[0] = z4; acc[1] = z4;
#pragma unroll 2
    for (int k0 = 0; k0 < 256; k0 += 32) {
        const bf16x8 a = *(const bf16x8*)(va + n * 264 + k0 + q * 8);
        bf16x8 b[2];
#pragma unroll
        for (int tc = 0; tc < 2; tc++)
            b[tc] = *(const bf16x8*)(Mb + (cw + tc * 16 + n) * 256 + k0 + q * 8);
#pragma unroll
        for (int tc = 0; tc < 2; tc++) acc[tc] = MFMA16(a, b[tc], acc[tc]);
    }
    const float bv = bg2[0];
#pragma unroll
    for (int tc = 0; tc < 2; tc++) {
        const int col = cw + tc * 16 + n;
#pragma unroll
        for (int r = 0; r < 4; r++)
            VX[(r0 + q * 4 + r) * 256 + col] = acc[tc][r] + bv;
    }
}

// ---------------------------------------------------------------------------
// K6: restore the real adjacency (fp32) — runs LAST.
// ---------------------------------------------------------------------------
__global__ __launch_bounds__(256) void k_adj(
    const float* __restrict__ gp, const int* __restrict__ iterp,
    float* __restrict__ adjOut) {
    const int o = blockIdx.x * 256 + threadIdx.x;  // o = j*256 + i
    const int j = o >> 8, i = o & 255;
    float g = 1.0f / (1.0f + expf(-gp[o]));
    if (i == j) g = 1.0f;
    if ((*iterp) > 50 && !(g > 0.1f)) g = 0.0f;
    adjOut[o] = g;
}

// ---------------------------------------------------------------------------
extern "C" void kernel_launch(void* const* d_in, const int* in_sizes, int n_in,
                              void* d_out, int out_size, void* d_ws, size_t ws_size,
                              hipStream_t stream) {
    const float* x    = (const float*)d_in[0];
    const float* eps  = (const float*)d_in[1];
    const float* Wenc = (const float*)d_in[2];
    const float* benc = (const float*)d_in[3];
    const float* Wmu  = (const float*)d_in[4];
    const float* bmu  = (const float*)d_in[5];
    const float* Wlv  = (const float*)d_in[6];
    const float* blv  = (const float*)d_in[7];
    const float* gp   = (const float*)d_in[8];
    const float* Wemb = (const float*)d_in[9];
    const float* bemb = (const float*)d_in[10];
    const float* Wg1  = (const float*)d_in[11];
    const float* bg1  = (const float*)d_in[12];
    const float* Wg2  = (const float*)d_in[13];
    const float* bg2  = (const float*)d_in[14];
    const int*   itr  = (const int*)d_in[15];
    (void)d_ws; (void)ws_size; (void)in_sizes; (void)n_in; (void)out_size;

    float* xhat = (float*)d_out;             // [8192,256] fp32
    float* adjO = xhat + ADJ_OFF;            // [256,256]  fp32
    float* muo  = xhat + MU_OFF;             // [8192,256] fp32
    float* lvo  = xhat + LV_OFF;             // [8192,256] fp32

    // Scratch carved from OUTPUT slots (zero d_ws footprint):
    //  adj slot (256 KB): Mb [0,128K) | wepack [128K,160K) | bepack(2log2e)
    //  [160K,192K) | colc int[256] [192K,193K) | rsO [193K,194K).
    //  Wt bf16 (384 KB) at xhat byte 4 MB: dead after k_ench.
    char* adjB = (char*)adjO;
    bf16_t* Mb     = (bf16_t*)adjB;
    bf16_t* wepack = (bf16_t*)(adjB + 131072);
    bf16_t* bepack = (bf16_t*)(adjB + 163840);
    int*    colc   = (int*)(adjB + 196608);
    float*  rsO    = (float*)(adjB + 197632);
    bf16_t* Wt     = (bf16_t*)((char*)d_out + 4194304);

    k_prep<<<dim3(50), dim3(256), 0, stream>>>(Wenc, Wmu, Wlv, Wemb, bemb,
                                               Wt, wepack, bepack, colc);
    k_deg <<<dim3(256), dim3(256), 0, stream>>>(gp, itr, colc, rsO);
    k_mkM <<<dim3(256), dim3(256), 0, stream>>>(gp, itr, colc, rsO, Mb);
    k_ench<<<dim3(512), dim3(512), 0, stream>>>(x, Wt, benc, bmu, blv, muo, lvo);
    k_gcn <<<dim3(2048), dim3(512), 0, stream>>>(muo, lvo, eps, wepack, bepack,
                                                 Wg1, bg1, Wg2, Mb, xhat);
    k_out <<<dim3(512), dim3(512), 0, stream>>>(xhat, Mb, bg2);
    k_adj <<<dim3(256), dim3(256), 0, stream>>>(gp, itr, adjO);
}

// Round 8
// 198.249 us; speedup vs baseline: 1.7918x; 1.0719x over previous
//
#include <hip/hip_runtime.h>

typedef __bf16 bf16_t;
typedef __bf16 bf16x4 __attribute__((ext_vector_type(4)));
typedef __bf16 bf16x8 __attribute__((ext_vector_type(8)));
typedef float  floatx4 __attribute__((ext_vector_type(4)));

#define MFMA16(a, b, c) __builtin_amdgcn_mfma_f32_16x16x32_bf16((a), (b), (c), 0, 0, 0)

// fp32 element offsets inside d_out
#define ADJ_OFF  2097152
#define MU_OFF   2162688
#define LV_OFF   4259840

#define TWO_LOG2E 2.8853900817779268f

// tanh(x) given argE2 = 2*log2(e)*x:  tanh = 1 - 2/(2^argE2 + 1).
// Saturates correctly at +-inf (exp2->inf/0 -> +-1), no NaN.
__device__ __forceinline__ float fast_tanh2(float argE2) {
    float e = __builtin_amdgcn_exp2f(argE2);
    return 1.0f - 2.0f * __builtin_amdgcn_rcpf(e + 1.0f);
}

__device__ __forceinline__ bf16x8 cvt8(const float* p) {
    const floatx4 a = *(const floatx4*)p;
    const floatx4 b = *(const floatx4*)(p + 4);
    bf16x8 r;
#pragma unroll
    for (int j = 0; j < 4; j++) { r[j] = (bf16_t)a[j]; r[4 + j] = (bf16_t)b[j]; }
    return r;
}

// ---------------------------------------------------------------------------
// K0: prep.  Blocks 0-47: LDS-tile transpose-cast of the 3 encoder weights.
// Block 48: wepack = bf16(Wemb * 2log2e).  Block 49: bepack = bf16(bemb *
// 2log2e) + zero colc.  (2log2e folded so tanh uses raw v_exp_f32.)
// ---------------------------------------------------------------------------
__global__ __launch_bounds__(256) void k_prep(
    const float* __restrict__ We, const float* __restrict__ Wm,
    const float* __restrict__ Wl, const float* __restrict__ Wemb,
    const float* __restrict__ bemb, bf16_t* __restrict__ Wt,
    bf16_t* __restrict__ wepack, bf16_t* __restrict__ bepack,
    int* __restrict__ colc) {
    __shared__ float tile[64][65];
    const int b = blockIdx.x, tid = threadIdx.x;
    if (b < 48) {
        const int m = b >> 4, t6 = b & 15;
        const int K0 = (t6 >> 2) << 6, N0 = (t6 & 3) << 6;
        const float* src = (m == 0) ? We : ((m == 1) ? Wm : Wl);
#pragma unroll
        for (int p = 0; p < 16; p++) {
            const int idx = p * 256 + tid;
            tile[idx >> 6][idx & 63] = src[(K0 + (idx >> 6)) * 256 + N0 + (idx & 63)];
        }
        __syncthreads();
        bf16_t* dst = Wt + m * 65536;
#pragma unroll
        for (int p = 0; p < 16; p++) {
            const int idx = p * 256 + tid;
            const int nn = idx >> 6, kk = idx & 63;
            dst[(N0 + nn) * 256 + K0 + kk] = (bf16_t)tile[kk][nn];
        }
    } else if (b == 48) {
#pragma unroll 4
        for (int p = 0; p < 64; p++)
            wepack[p * 256 + tid] = (bf16_t)(TWO_LOG2E * Wemb[p * 256 + tid]);
    } else {
        colc[tid] = 0;
#pragma unroll 4
        for (int p = 0; p < 64; p++)
            bepack[p * 256 + tid] = (bf16_t)(TWO_LOG2E * bemb[p * 256 + tid]);
    }
}

// ---------------------------------------------------------------------------
// K1: degrees, 256 blocks (block j = adjacency row j).
// ---------------------------------------------------------------------------
__global__ __launch_bounds__(256) void k_deg(
    const float* __restrict__ gp, const int* __restrict__ iterp,
    int* __restrict__ colc, float* __restrict__ rsO) {
    __shared__ unsigned long long mk[4];
    const int j = blockIdx.x, t = threadIdx.x;
    const bool thr = (*iterp) > 50;
    float g = 1.0f / (1.0f + expf(-gp[j * 256 + t]));
    if (t == j) g = 1.0f;
    if (thr && !(g > 0.1f)) g = 0.0f;
    const bool nz = (g != 0.0f);
    const unsigned long long bal = __ballot(nz);
    if ((t & 63) == 0) mk[t >> 6] = bal;
    if (nz) atomicAdd(&colc[t], 1);
    __syncthreads();
    if (t == 0) {
        const int rc = (int)(__popcll(mk[0]) + __popcll(mk[1]) +
                             __popcll(mk[2]) + __popcll(mk[3]));
        rsO[j] = rsqrtf((float)(rc < 1 ? 1 : rc));
    }
}

// ---------------------------------------------------------------------------
// K2: M bf16.  Block j, thread t: M[t][j] = adj[j][t]*rsO[j]*rsI[t].
// ---------------------------------------------------------------------------
__global__ __launch_bounds__(256) void k_mkM(
    const float* __restrict__ gp, const int* __restrict__ iterp,
    const int* __restrict__ colc, const float* __restrict__ rsO,
    bf16_t* __restrict__ Mb) {
    const int j = blockIdx.x, t = threadIdx.x;
    const int ci = colc[t];
    const float rsi = rsqrtf((float)(ci < 1 ? 1 : ci));
    float g = 1.0f / (1.0f + expf(-gp[j * 256 + t]));
    if (t == j) g = 1.0f;
    if ((*iterp) > 50 && !(g > 0.1f)) g = 0.0f;
    Mb[t * 256 + j] = (bf16_t)(g * rsO[j] * rsi);
}

// ---------------------------------------------------------------------------
// K3: fused encoder+heads v3.  256 blocks x 512 thr, 32-row bands (was 16).
// Same amortization lever as k_gcn BL=4 (round 7, -33%): per-block fixed
// costs and full-Wt L2 re-reads (384 KB/block) halve.  Each wave: 2 row-
// tiles x 2 col-tiles.  LDS: 2 x 32x264 bf16 = 33.8 KB.
// ---------------------------------------------------------------------------
__global__ __launch_bounds__(512) void k_ench(
    const float* __restrict__ X, const bf16_t* __restrict__ Wt,
    const float* __restrict__ benc, const float* __restrict__ bmu,
    const float* __restrict__ blv,
    float* __restrict__ MuOut, float* __restrict__ LvOut) {
    __shared__ __align__(16) bf16_t Xs[32 * 264];
    __shared__ __align__(16) bf16_t Hs[32 * 264];
    const bf16_t* Bte = Wt;
    const bf16_t* Btm = Wt + 65536;
    const bf16_t* Btl = Wt + 131072;
    const int tid = threadIdx.x;
    const int r0 = blockIdx.x * 32;
    const int w = tid >> 6;
    const int lane = tid & 63;
    const int n = lane & 15, q = lane >> 4;
    const int cw = w * 32;
    const floatx4 z4 = {0.f, 0.f, 0.f, 0.f};

    // stage X band [32 x 256] fp32 -> bf16 LDS (16 elems/thread, coalesced)
#pragma unroll
    for (int p = 0; p < 2; p++) {
        const int e0 = (p * 512 + tid) * 8;
        const int row = e0 >> 8, col = e0 & 255;
        *(bf16x8*)(Xs + row * 264 + col) = cvt8(X + (r0 + row) * 256 + col);
    }
    __syncthreads();

    // ---- phase A: H = relu(Xs @ We + be) ----
    floatx4 ah[2][2];
#pragma unroll
    for (int rt = 0; rt < 2; rt++)
#pragma unroll
        for (int tc = 0; tc < 2; tc++) ah[rt][tc] = z4;
#pragma unroll 2
    for (int k0 = 0; k0 < 256; k0 += 32) {
        bf16x8 a[2], b[2];
#pragma unroll
        for (int rt = 0; rt < 2; rt++)
            a[rt] = *(const bf16x8*)(Xs + (rt * 16 + n) * 264 + k0 + q * 8);
#pragma unroll
        for (int tc = 0; tc < 2; tc++)
            b[tc] = *(const bf16x8*)(Bte + (cw + tc * 16 + n) * 256 + k0 + q * 8);
#pragma unroll
        for (int rt = 0; rt < 2; rt++)
#pragma unroll
            for (int tc = 0; tc < 2; tc++)
                ah[rt][tc] = MFMA16(a[rt], b[tc], ah[rt][tc]);
    }
#pragma unroll
    for (int tc = 0; tc < 2; tc++) {
        const int col = cw + tc * 16 + n;
        const float bv = benc[col];
#pragma unroll
        for (int rt = 0; rt < 2; rt++)
#pragma unroll
            for (int r = 0; r < 4; r++)
                Hs[(rt * 16 + q * 4 + r) * 264 + col] =
                    (bf16_t)fmaxf(ah[rt][tc][r] + bv, 0.0f);
    }
    __syncthreads();

    // ---- phase B: mu/lv = Hs @ {Wm,Wl} + b ----
    floatx4 am[2][2], al[2][2];
#pragma unroll
    for (int rt = 0; rt < 2; rt++)
#pragma unroll
        for (int tc = 0; tc < 2; tc++) { am[rt][tc] = z4; al[rt][tc] = z4; }
#pragma unroll 2
    for (int k0 = 0; k0 < 256; k0 += 32) {
        bf16x8 a[2], bm_[2], bl_[2];
#pragma unroll
        for (int rt = 0; rt < 2; rt++)
            a[rt] = *(const bf16x8*)(Hs + (rt * 16 + n) * 264 + k0 + q * 8);
#pragma unroll
        for (int tc = 0; tc < 2; tc++) {
            bm_[tc] = *(const bf16x8*)(Btm + (cw + tc * 16 + n) * 256 + k0 + q * 8);
            bl_[tc] = *(const bf16x8*)(Btl + (cw + tc * 16 + n) * 256 + k0 + q * 8);
        }
#pragma unroll
        for (int rt = 0; rt < 2; rt++)
#pragma unroll
            for (int tc = 0; tc < 2; tc++) {
                am[rt][tc] = MFMA16(a[rt], bm_[tc], am[rt][tc]);
                al[rt][tc] = MFMA16(a[rt], bl_[tc], al[rt][tc]);
            }
    }
#pragma unroll
    for (int tc = 0; tc < 2; tc++) {
        const int col = cw + tc * 16 + n;
        const float bmv = bmu[col], blvv = blv[col];
#pragma unroll
        for (int rt = 0; rt < 2; rt++)
#pragma unroll
            for (int r = 0; r < 4; r++) {
                const int row = r0 + rt * 16 + q * 4 + r;
                MuOut[row * 256 + col] = am[rt][tc][r] + bmv;
                LvOut[row * 256 + col] = al[rt][tc][r] + blvv;
            }
    }
}

// ---------------------------------------------------------------------------
// K4: fused GCN v10b (round 7, 77.5us).  2048 blocks x 512 thr, 4 rows/blk.
// Spill invariant: WRITE_SIZE == 8192 KB.
// ---------------------------------------------------------------------------
__global__ __launch_bounds__(512, 4) void k_gcn(
    const float* __restrict__ Mu, const float* __restrict__ Lv,
    const float* __restrict__ Eps, const bf16_t* __restrict__ wepack,
    const bf16_t* __restrict__ bepack, const float* __restrict__ Wg1,
    const float* __restrict__ bg1, const float* __restrict__ Wg2,
    const bf16_t* __restrict__ Mb, float* __restrict__ Vout) {
    __shared__ __align__(16) bf16_t smem[128 * 256];   // 64 KB: 4 bl x 32 e
    __shared__ float zs[1024];
    const int tid = threadIdx.x;
    const int lane = tid & 63;
    const int w = tid >> 6;                 // wave 0..7
    const int n = lane & 15, q = lane >> 4;
    const int bg = blockIdx.x;              // batch quad
    const floatx4 z4 = {0.f, 0.f, 0.f, 0.f};

    // stage z for 4 rows (coalesced fp32 reads, 2 elems/thread)
    {
        const int gi = bg * 1024 + tid;
        zs[tid] = fmaf(Eps[gi], __expf(0.5f * Lv[gi]), Mu[gi]);
        const int gi2 = gi + 512;
        zs[tid + 512] = fmaf(Eps[gi2], __expf(0.5f * Lv[gi2]), Mu[gi2]);
    }

    // preload W_g1 B-fragments
    bf16x8 wg1f[2][2];
#pragma unroll
    for (int ks = 0; ks < 2; ks++)
#pragma unroll
        for (int te = 0; te < 2; te++)
#pragma unroll
            for (int j = 0; j < 8; j++)
                wg1f[ks][te][j] = (bf16_t)Wg1[(ks * 32 + q * 8 + j) * 32 + te * 16 + n];
    __syncthreads();

    // ---- phase 1: wave w -> j-tiles {2w, 2w+1}, each for bl 0..3 ----
#pragma unroll
    for (int jt2 = 0; jt2 < 2; jt2++) {
        const int j0 = (w * 2 + jt2) * 16;
        const int jA = j0 + n;
        // table fragments loaded ONCE per j-tile, reused for 4 batch rows
        const bf16x8 we0 = *(const bf16x8*)(wepack + jA * 64 + q * 8);
        const bf16x8 we1 = *(const bf16x8*)(wepack + jA * 64 + 32 + q * 8);
        const bf16x8 be0 = *(const bf16x8*)(bepack + jA * 64 + q * 8);
        const bf16x8 be1 = *(const bf16x8*)(bepack + jA * 64 + 32 + q * 8);
        const int j8a = (j0 >> 3) + (q >> 1);
        const int jlo = (q & 1) * 4;
        const int sw = ((j8a ^ (n & 7)) << 3) + jlo;
#pragma unroll
        for (int bl = 0; bl < 4; bl++) {
            const float zv = zs[bl * 256 + jA];   // 2log2e folded into packs
            bf16x8 a0, a1;
#pragma unroll
            for (int j = 0; j < 8; j++) {
                a0[j] = (bf16_t)fast_tanh2(fmaf(zv, (float)we0[j], (float)be0[j]));
                a1[j] = (bf16_t)fast_tanh2(fmaf(zv, (float)we1[j], (float)be1[j]));
            }
            floatx4 c0 = z4, c1 = z4;
            c0 = MFMA16(a0, wg1f[0][0], c0);
            c0 = MFMA16(a1, wg1f[1][0], c0);
            c1 = MFMA16(a0, wg1f[0][1], c1);
            c1 = MFMA16(a1, wg1f[1][1], c1);
            bf16x4 s0, s1;
#pragma unroll
            for (int r = 0; r < 4; r++) { s0[r] = (bf16_t)c0[r]; s1[r] = (bf16_t)c1[r]; }
            *(bf16x4*)(smem + (bl * 32 + n) * 256 + sw) = s0;        // e = n
            *(bf16x4*)(smem + (bl * 32 + 16 + n) * 256 + sw) = s1;   // e = 16+n
        }
    }
    __syncthreads();

    // ---- phase 2: T1 = M @ Q (wave w: i in [w*32,w*32+32), c in [0,128)) --
    const int i0 = w * 32;
    floatx4 acc[2][8];
#pragma unroll
    for (int ti = 0; ti < 2; ti++)
#pragma unroll
        for (int tc = 0; tc < 8; tc++) acc[ti][tc] = z4;
#pragma unroll
    for (int k0 = 0; k0 < 256; k0 += 32) {
        const int k8 = k0 >> 3;
        bf16x8 a[2], b[8];
#pragma unroll
        for (int ti = 0; ti < 2; ti++)
            a[ti] = *(const bf16x8*)(Mb + (i0 + ti * 16 + n) * 256 + k0 + q * 8);
#pragma unroll
        for (int tc = 0; tc < 8; tc++)
            b[tc] = *(const bf16x8*)(smem + (tc * 16 + n) * 256 +
                                     (((k8 + q) ^ (n & 7)) << 3));
        __builtin_amdgcn_s_setprio(1);
#pragma unroll
        for (int ti = 0; ti < 2; ti++)
#pragma unroll
            for (int tc = 0; tc < 8; tc++)
                acc[ti][tc] = MFMA16(a[ti], b[tc], acc[ti][tc]);
        __builtin_amdgcn_s_setprio(0);
    }

    // ---- epilogue: in-register relu+Wg2 contraction + reduce-scatter ----
    // lane covers e = n (tc even) and e = 16+n (tc odd); bl = tc>>1 in 0..3.
    const float w2a = Wg2[n],      w2b = Wg2[16 + n];
    const float b1a = bg1[n],      b1b = bg1[16 + n];
    float v32[32];   // k = bl*8 + ti*4 + r
#pragma unroll
    for (int bl = 0; bl < 4; bl++)
#pragma unroll
        for (int ti = 0; ti < 2; ti++)
#pragma unroll
            for (int r = 0; r < 4; r++)
                v32[bl * 8 + ti * 4 + r] =
                    fmaxf(acc[ti][2 * bl][r] + b1a, 0.0f) * w2a +
                    fmaxf(acc[ti][2 * bl + 1][r] + b1b, 0.0f) * w2b;
    // reduce-scatter over lane bits 0..3; lane ends with k = n and k = 16+n.
    const bool h0 = (lane & 1), h1_ = (lane & 2), h2 = (lane & 4), h3 = (lane & 8);
    float u16[16];
#pragma unroll
    for (int p = 0; p < 16; p++) {
        const float keep = h0 ? v32[2 * p + 1] : v32[2 * p];
        const float send = h0 ? v32[2 * p] : v32[2 * p + 1];
        u16[p] = keep + __shfl_xor(send, 1, 64);
    }
    float u8[8];
#pragma unroll
    for (int p = 0; p < 8; p++) {
        const float keep = h1_ ? u16[2 * p + 1] : u16[2 * p];
        const float send = h1_ ? u16[2 * p] : u16[2 * p + 1];
        u8[p] = keep + __shfl_xor(send, 2, 64);
    }
    float u4[4];
#pragma unroll
    for (int p = 0; p < 4; p++) {
        const float keep = h2 ? u8[2 * p + 1] : u8[2 * p];
        const float send = h2 ? u8[2 * p] : u8[2 * p + 1];
        u4[p] = keep + __shfl_xor(send, 4, 64);
    }
    float u2[2];
#pragma unroll
    for (int p = 0; p < 2; p++) {
        const float keep = h3 ? u4[2 * p + 1] : u4[2 * p];
        const float send = h3 ? u4[2 * p] : u4[2 * p + 1];
        u2[p] = keep + __shfl_xor(send, 8, 64);
    }
    {
        // lane holds k = 16*p + n: r = n&3, ti = (n>>2)&1, bl = p*2 + (n>>3)
        const int i_out = i0 + ((n >> 2) & 1) * 16 + q * 4 + (n & 3);
        const int blv = n >> 3;
        Vout[bg * 1024 + blv * 256 + i_out] = u2[0];
        Vout[bg * 1024 + (2 + blv) * 256 + i_out] = u2[1];
    }
}

// ---------------------------------------------------------------------------
// K5: x_hat = V @ M^T + b_g2, in place.  256 blocks, 32-row bands (was 16).
// Same amortization: per-block Mb re-read (128 KB) and fixed costs halve.
// ---------------------------------------------------------------------------
__global__ __launch_bounds__(512) void k_out(
    float* __restrict__ VX, const bf16_t* __restrict__ Mb,
    const float* __restrict__ bg2) {
    __shared__ __align__(16) bf16_t va[32 * 264];
    const int tid = threadIdx.x;
    const int lane = tid & 63;
    const int w = tid >> 6;                 // wave 0..7 -> col group
    const int n = lane & 15, q = lane >> 4;
    const int r0 = blockIdx.x * 32;

#pragma unroll
    for (int p = 0; p < 4; p++) {
        const int i4 = p * 512 + tid;
        const int row = i4 >> 6, c4 = (i4 & 63) * 4;
        const floatx4 v = *(const floatx4*)(VX + (r0 + row) * 256 + c4);
        bf16x4 s;
#pragma unroll
        for (int r = 0; r < 4; r++) s[r] = (bf16_t)v[r];
        *(bf16x4*)(va + row * 264 + c4) = s;
    }
    __syncthreads();

    const int cw = w * 32;
    const floatx4 z4 = {0.f, 0.f, 0.f, 0.f};
    floatx4 acc[2][2];
#pragma unroll
    for (int rt = 0; rt < 2; rt++)
#pragma unroll
        for (int tc = 0; tc < 2; tc++) acc[rt][tc] = z4;
#pragma unroll 2
    for (int k0 = 0; k0 < 256; k0 += 32) {
        bf16x8 a[2], b[2];
#pragma unroll
        for (int rt = 0; rt < 2; rt++)
            a[rt] = *(const bf16x8*)(va + (rt * 16 + n) * 264 + k0 + q * 8);
#pragma unroll
        for (int tc = 0; tc < 2; tc++)
            b[tc] = *(const bf16x8*)(Mb + (cw + tc * 16 + n) * 256 + k0 + q * 8);
#pragma unroll
        for (int rt = 0; rt < 2; rt++)
#pragma unroll
            for (int tc = 0; tc < 2; tc++)
                acc[rt][tc] = MFMA16(a[rt], b[tc], acc[rt][tc]);
    }
    const float bv = bg2[0];
#pragma unroll
    for (int tc = 0; tc < 2; tc++) {
        const int col = cw + tc * 16 + n;
#pragma unroll
        for (int rt = 0; rt < 2; rt++)
#pragma unroll
            for (int r = 0; r < 4; r++)
                VX[(r0 + rt * 16 + q * 4 + r) * 256 + col] = acc[rt][tc][r] + bv;
    }
}

// ---------------------------------------------------------------------------
// K6: restore the real adjacency (fp32) — runs LAST.
// ---------------------------------------------------------------------------
__global__ __launch_bounds__(256) void k_adj(
    const float* __restrict__ gp, const int* __restrict__ iterp,
    float* __restrict__ adjOut) {
    const int o = blockIdx.x * 256 + threadIdx.x;  // o = j*256 + i
    const int j = o >> 8, i = o & 255;
    float g = 1.0f / (1.0f + expf(-gp[o]));
    if (i == j) g = 1.0f;
    if ((*iterp) > 50 && !(g > 0.1f)) g = 0.0f;
    adjOut[o] = g;
}

// ---------------------------------------------------------------------------
extern "C" void kernel_launch(void* const* d_in, const int* in_sizes, int n_in,
                              void* d_out, int out_size, void* d_ws, size_t ws_size,
                              hipStream_t stream) {
    const float* x    = (const float*)d_in[0];
    const float* eps  = (const float*)d_in[1];
    const float* Wenc = (const float*)d_in[2];
    const float* benc = (const float*)d_in[3];
    const float* Wmu  = (const float*)d_in[4];
    const float* bmu  = (const float*)d_in[5];
    const float* Wlv  = (const float*)d_in[6];
    const float* blv  = (const float*)d_in[7];
    const float* gp   = (const float*)d_in[8];
    const float* Wemb = (const float*)d_in[9];
    const float* bemb = (const float*)d_in[10];
    const float* Wg1  = (const float*)d_in[11];
    const float* bg1  = (const float*)d_in[12];
    const float* Wg2  = (const float*)d_in[13];
    const float* bg2  = (const float*)d_in[14];
    const int*   itr  = (const int*)d_in[15];
    (void)d_ws; (void)ws_size; (void)in_sizes; (void)n_in; (void)out_size;

    float* xhat = (float*)d_out;             // [8192,256] fp32
    float* adjO = xhat + ADJ_OFF;            // [256,256]  fp32
    float* muo  = xhat + MU_OFF;             // [8192,256] fp32
    float* lvo  = xhat + LV_OFF;             // [8192,256] fp32

    // Scratch carved from OUTPUT slots (zero d_ws footprint):
    //  adj slot (256 KB): Mb [0,128K) | wepack [128K,160K) | bepack(2log2e)
    //  [160K,192K) | colc int[256] [192K,193K) | rsO [193K,194K).
    //  Wt bf16 (384 KB) at xhat byte 4 MB: dead after k_ench.
    char* adjB = (char*)adjO;
    bf16_t* Mb     = (bf16_t*)adjB;
    bf16_t* wepack = (bf16_t*)(adjB + 131072);
    bf16_t* bepack = (bf16_t*)(adjB + 163840);
    int*    colc   = (int*)(adjB + 196608);
    float*  rsO    = (float*)(adjB + 197632);
    bf16_t* Wt     = (bf16_t*)((char*)d_out + 4194304);

    k_prep<<<dim3(50), dim3(256), 0, stream>>>(Wenc, Wmu, Wlv, Wemb, bemb,
                                               Wt, wepack, bepack, colc);
    k_deg <<<dim3(256), dim3(256), 0, stream>>>(gp, itr, colc, rsO);
    k_mkM <<<dim3(256), dim3(256), 0, stream>>>(gp, itr, colc, rsO, Mb);
    k_ench<<<dim3(256), dim3(512), 0, stream>>>(x, Wt, benc, bmu, blv, muo, lvo);
    k_gcn <<<dim3(2048), dim3(512), 0, stream>>>(muo, lvo, eps, wepack, bepack,
                                                 Wg1, bg1, Wg2, Mb, xhat);
    k_out <<<dim3(256), dim3(512), 0, stream>>>(xhat, Mb, bg2);
    k_adj <<<dim3(256), dim3(256), 0, stream>>>(gp, itr, adjO);
}

// Round 9
// 192.509 us; speedup vs baseline: 1.8453x; 1.0298x over previous
//
#include <hip/hip_runtime.h>

typedef __bf16 bf16_t;
typedef __bf16 bf16x4 __attribute__((ext_vector_type(4)));
typedef __bf16 bf16x8 __attribute__((ext_vector_type(8)));
typedef float  floatx4 __attribute__((ext_vector_type(4)));

#define MFMA16(a, b, c) __builtin_amdgcn_mfma_f32_16x16x32_bf16((a), (b), (c), 0, 0, 0)

// fp32 element offsets inside d_out
#define ADJ_OFF  2097152
#define MU_OFF   2162688
#define LV_OFF   4259840

#define TWO_LOG2E 2.8853900817779268f

// tanh(x) given argE2 = 2*log2(e)*x:  tanh = 1 - 2/(2^argE2 + 1).
// Saturates correctly at +-inf (exp2->inf/0 -> +-1), no NaN.
__device__ __forceinline__ float fast_tanh2(float argE2) {
    float e = __builtin_amdgcn_exp2f(argE2);
    return 1.0f - 2.0f * __builtin_amdgcn_rcpf(e + 1.0f);
}

__device__ __forceinline__ bf16x8 cvt8(const float* p) {
    const floatx4 a = *(const floatx4*)p;
    const floatx4 b = *(const floatx4*)(p + 4);
    bf16x8 r;
#pragma unroll
    for (int j = 0; j < 4; j++) { r[j] = (bf16_t)a[j]; r[4 + j] = (bf16_t)b[j]; }
    return r;
}

// ---------------------------------------------------------------------------
// K0: prep, 208 blocks (was 50 — 4/5 of the GPU sat idle).
// Blocks 0-191: 32x32-tile transpose-cast of the 3 encoder weights.
// Blocks 192-199: wepack = bf16(Wemb*2log2e).  200-207: bepack (+colc=0).
// ---------------------------------------------------------------------------
__global__ __launch_bounds__(256) void k_prep(
    const float* __restrict__ We, const float* __restrict__ Wm,
    const float* __restrict__ Wl, const float* __restrict__ Wemb,
    const float* __restrict__ bemb, bf16_t* __restrict__ Wt,
    bf16_t* __restrict__ wepack, bf16_t* __restrict__ bepack,
    int* __restrict__ colc) {
    __shared__ float tile[32][33];
    const int b = blockIdx.x, tid = threadIdx.x;
    if (b < 192) {
        const int m = b >> 6, t6 = b & 63;
        const int K0 = (t6 >> 3) << 5, N0 = (t6 & 7) << 5;
        const float* src = (m == 0) ? We : ((m == 1) ? Wm : Wl);
#pragma unroll
        for (int p = 0; p < 4; p++) {
            const int idx = p * 256 + tid;
            tile[idx >> 5][idx & 31] = src[(K0 + (idx >> 5)) * 256 + N0 + (idx & 31)];
        }
        __syncthreads();
        bf16_t* dst = Wt + m * 65536;
#pragma unroll
        for (int p = 0; p < 4; p++) {
            const int idx = p * 256 + tid;
            const int nn = idx >> 5, kk = idx & 31;
            dst[(N0 + nn) * 256 + K0 + kk] = (bf16_t)tile[kk][nn];
        }
    } else if (b < 200) {
        const int base = (b - 192) * 2048;
#pragma unroll
        for (int p = 0; p < 8; p++) {
            const int idx = base + p * 256 + tid;
            wepack[idx] = (bf16_t)(TWO_LOG2E * Wemb[idx]);
        }
    } else {
        if (b == 200) colc[tid] = 0;
        const int base = (b - 200) * 2048;
#pragma unroll
        for (int p = 0; p < 8; p++) {
            const int idx = base + p * 256 + tid;
            bepack[idx] = (bf16_t)(TWO_LOG2E * bemb[idx]);
        }
    }
}

// ---------------------------------------------------------------------------
// K1: degrees, 256 blocks (block j = adjacency row j).
// ---------------------------------------------------------------------------
__global__ __launch_bounds__(256) void k_deg(
    const float* __restrict__ gp, const int* __restrict__ iterp,
    int* __restrict__ colc, float* __restrict__ rsO) {
    __shared__ unsigned long long mk[4];
    const int j = blockIdx.x, t = threadIdx.x;
    const bool thr = (*iterp) > 50;
    float g = 1.0f / (1.0f + expf(-gp[j * 256 + t]));
    if (t == j) g = 1.0f;
    if (thr && !(g > 0.1f)) g = 0.0f;
    const bool nz = (g != 0.0f);
    const unsigned long long bal = __ballot(nz);
    if ((t & 63) == 0) mk[t >> 6] = bal;
    if (nz) atomicAdd(&colc[t], 1);
    __syncthreads();
    if (t == 0) {
        const int rc = (int)(__popcll(mk[0]) + __popcll(mk[1]) +
                             __popcll(mk[2]) + __popcll(mk[3]));
        rsO[j] = rsqrtf((float)(rc < 1 ? 1 : rc));
    }
}

// ---------------------------------------------------------------------------
// K2: M bf16 + (optionally) the fp32 adjacency output.  When scratch lives
// in d_ws, the adj output slot is free from the start, so k_mkM writes it
// directly (it already computes g) and k_adj is ELIMINATED.
// ---------------------------------------------------------------------------
__global__ __launch_bounds__(256) void k_mkM(
    const float* __restrict__ gp, const int* __restrict__ iterp,
    const int* __restrict__ colc, const float* __restrict__ rsO,
    bf16_t* __restrict__ Mb, float* __restrict__ adjOut) {
    const int j = blockIdx.x, t = threadIdx.x;
    const int ci = colc[t];
    const float rsi = rsqrtf((float)(ci < 1 ? 1 : ci));
    float g = 1.0f / (1.0f + expf(-gp[j * 256 + t]));
    if (t == j) g = 1.0f;
    if ((*iterp) > 50 && !(g > 0.1f)) g = 0.0f;
    if (adjOut) adjOut[j * 256 + t] = g;
    Mb[t * 256 + j] = (bf16_t)(g * rsO[j] * rsi);
}

// ---------------------------------------------------------------------------
// K3: fused encoder+heads v3.  256 blocks x 512 thr, 32-row bands.
// ---------------------------------------------------------------------------
__global__ __launch_bounds__(512) void k_ench(
    const float* __restrict__ X, const bf16_t* __restrict__ Wt,
    const float* __restrict__ benc, const float* __restrict__ bmu,
    const float* __restrict__ blv,
    float* __restrict__ MuOut, float* __restrict__ LvOut) {
    __shared__ __align__(16) bf16_t Xs[32 * 264];
    __shared__ __align__(16) bf16_t Hs[32 * 264];
    const bf16_t* Bte = Wt;
    const bf16_t* Btm = Wt + 65536;
    const bf16_t* Btl = Wt + 131072;
    const int tid = threadIdx.x;
    const int r0 = blockIdx.x * 32;
    const int w = tid >> 6;
    const int lane = tid & 63;
    const int n = lane & 15, q = lane >> 4;
    const int cw = w * 32;
    const floatx4 z4 = {0.f, 0.f, 0.f, 0.f};

    // stage X band [32 x 256] fp32 -> bf16 LDS (16 elems/thread, coalesced)
#pragma unroll
    for (int p = 0; p < 2; p++) {
        const int e0 = (p * 512 + tid) * 8;
        const int row = e0 >> 8, col = e0 & 255;
        *(bf16x8*)(Xs + row * 264 + col) = cvt8(X + (r0 + row) * 256 + col);
    }
    __syncthreads();

    // ---- phase A: H = relu(Xs @ We + be) ----
    floatx4 ah[2][2];
#pragma unroll
    for (int rt = 0; rt < 2; rt++)
#pragma unroll
        for (int tc = 0; tc < 2; tc++) ah[rt][tc] = z4;
#pragma unroll 2
    for (int k0 = 0; k0 < 256; k0 += 32) {
        bf16x8 a[2], b[2];
#pragma unroll
        for (int rt = 0; rt < 2; rt++)
            a[rt] = *(const bf16x8*)(Xs + (rt * 16 + n) * 264 + k0 + q * 8);
#pragma unroll
        for (int tc = 0; tc < 2; tc++)
            b[tc] = *(const bf16x8*)(Bte + (cw + tc * 16 + n) * 256 + k0 + q * 8);
#pragma unroll
        for (int rt = 0; rt < 2; rt++)
#pragma unroll
            for (int tc = 0; tc < 2; tc++)
                ah[rt][tc] = MFMA16(a[rt], b[tc], ah[rt][tc]);
    }
#pragma unroll
    for (int tc = 0; tc < 2; tc++) {
        const int col = cw + tc * 16 + n;
        const float bv = benc[col];
#pragma unroll
        for (int rt = 0; rt < 2; rt++)
#pragma unroll
            for (int r = 0; r < 4; r++)
                Hs[(rt * 16 + q * 4 + r) * 264 + col] =
                    (bf16_t)fmaxf(ah[rt][tc][r] + bv, 0.0f);
    }
    __syncthreads();

    // ---- phase B: mu/lv = Hs @ {Wm,Wl} + b ----
    floatx4 am[2][2], al[2][2];
#pragma unroll
    for (int rt = 0; rt < 2; rt++)
#pragma unroll
        for (int tc = 0; tc < 2; tc++) { am[rt][tc] = z4; al[rt][tc] = z4; }
#pragma unroll 2
    for (int k0 = 0; k0 < 256; k0 += 32) {
        bf16x8 a[2], bm_[2], bl_[2];
#pragma unroll
        for (int rt = 0; rt < 2; rt++)
            a[rt] = *(const bf16x8*)(Hs + (rt * 16 + n) * 264 + k0 + q * 8);
#pragma unroll
        for (int tc = 0; tc < 2; tc++) {
            bm_[tc] = *(const bf16x8*)(Btm + (cw + tc * 16 + n) * 256 + k0 + q * 8);
            bl_[tc] = *(const bf16x8*)(Btl + (cw + tc * 16 + n) * 256 + k0 + q * 8);
        }
#pragma unroll
        for (int rt = 0; rt < 2; rt++)
#pragma unroll
            for (int tc = 0; tc < 2; tc++) {
                am[rt][tc] = MFMA16(a[rt], bm_[tc], am[rt][tc]);
                al[rt][tc] = MFMA16(a[rt], bl_[tc], al[rt][tc]);
            }
    }
#pragma unroll
    for (int tc = 0; tc < 2; tc++) {
        const int col = cw + tc * 16 + n;
        const float bmv = bmu[col], blvv = blv[col];
#pragma unroll
        for (int rt = 0; rt < 2; rt++)
#pragma unroll
            for (int r = 0; r < 4; r++) {
                const int row = r0 + rt * 16 + q * 4 + r;
                MuOut[row * 256 + col] = am[rt][tc][r] + bmv;
                LvOut[row * 256 + col] = al[rt][tc][r] + blvv;
            }
    }
}

// ---------------------------------------------------------------------------
// K4: fused GCN v11.  2048 blocks x 512 thr, 4 batch rows/block.
// Delta vs round-7 (77.5us): phase-1 we/be bf16->f32 cvts hoisted OUT of
// the bl loop (convert once per j-tile into f32 arrays; loads stay bf16).
// Kills 96 redundant cvts/thread/jt2.  Phase-1 peak regs (~60) < phase-2
// peak (~110) -> kernel peak unchanged, no spill by construction.
// Spill invariant: WRITE_SIZE == 8192 KB.
// ---------------------------------------------------------------------------
__global__ __launch_bounds__(512, 4) void k_gcn(
    const float* __restrict__ Mu, const float* __restrict__ Lv,
    const float* __restrict__ Eps, const bf16_t* __restrict__ wepack,
    const bf16_t* __restrict__ bepack, const float* __restrict__ Wg1,
    const float* __restrict__ bg1, const float* __restrict__ Wg2,
    const bf16_t* __restrict__ Mb, float* __restrict__ Vout) {
    __shared__ __align__(16) bf16_t smem[128 * 256];   // 64 KB: 4 bl x 32 e
    __shared__ float zs[1024];
    const int tid = threadIdx.x;
    const int lane = tid & 63;
    const int w = tid >> 6;                 // wave 0..7
    const int n = lane & 15, q = lane >> 4;
    const int bg = blockIdx.x;              // batch quad
    const floatx4 z4 = {0.f, 0.f, 0.f, 0.f};

    // stage z for 4 rows (coalesced fp32 reads, 2 elems/thread)
    {
        const int gi = bg * 1024 + tid;
        zs[tid] = fmaf(Eps[gi], __expf(0.5f * Lv[gi]), Mu[gi]);
        const int gi2 = gi + 512;
        zs[tid + 512] = fmaf(Eps[gi2], __expf(0.5f * Lv[gi2]), Mu[gi2]);
    }

    // preload W_g1 B-fragments
    bf16x8 wg1f[2][2];
#pragma unroll
    for (int ks = 0; ks < 2; ks++)
#pragma unroll
        for (int te = 0; te < 2; te++)
#pragma unroll
            for (int j = 0; j < 8; j++)
                wg1f[ks][te][j] = (bf16_t)Wg1[(ks * 32 + q * 8 + j) * 32 + te * 16 + n];
    __syncthreads();

    // ---- phase 1: wave w -> j-tiles {2w, 2w+1}, each for bl 0..3 ----
#pragma unroll
    for (int jt2 = 0; jt2 < 2; jt2++) {
        const int j0 = (w * 2 + jt2) * 16;
        const int jA = j0 + n;
        // bf16 table fragments loaded once per j-tile; cvt to f32 ONCE
        // (hoisted out of the bl loop), reused for 4 batch rows.
        const bf16x8 we0 = *(const bf16x8*)(wepack + jA * 64 + q * 8);
        const bf16x8 we1 = *(const bf16x8*)(wepack + jA * 64 + 32 + q * 8);
        const bf16x8 be0 = *(const bf16x8*)(bepack + jA * 64 + q * 8);
        const bf16x8 be1 = *(const bf16x8*)(bepack + jA * 64 + 32 + q * 8);
        float wf0[8], wf1[8], bf0[8], bf1[8];
#pragma unroll
        for (int j = 0; j < 8; j++) {
            wf0[j] = (float)we0[j]; wf1[j] = (float)we1[j];
            bf0[j] = (float)be0[j]; bf1[j] = (float)be1[j];
        }
        const int j8a = (j0 >> 3) + (q >> 1);
        const int jlo = (q & 1) * 4;
        const int sw = ((j8a ^ (n & 7)) << 3) + jlo;
#pragma unroll
        for (int bl = 0; bl < 4; bl++) {
            const float zv = zs[bl * 256 + jA];   // 2log2e folded into packs
            bf16x8 a0, a1;
#pragma unroll
            for (int j = 0; j < 8; j++) {
                a0[j] = (bf16_t)fast_tanh2(fmaf(zv, wf0[j], bf0[j]));
                a1[j] = (bf16_t)fast_tanh2(fmaf(zv, wf1[j], bf1[j]));
            }
            floatx4 c0 = z4, c1 = z4;
            c0 = MFMA16(a0, wg1f[0][0], c0);
            c0 = MFMA16(a1, wg1f[1][0], c0);
            c1 = MFMA16(a0, wg1f[0][1], c1);
            c1 = MFMA16(a1, wg1f[1][1], c1);
            bf16x4 s0, s1;
#pragma unroll
            for (int r = 0; r < 4; r++) { s0[r] = (bf16_t)c0[r]; s1[r] = (bf16_t)c1[r]; }
            *(bf16x4*)(smem + (bl * 32 + n) * 256 + sw) = s0;        // e = n
            *(bf16x4*)(smem + (bl * 32 + 16 + n) * 256 + sw) = s1;   // e = 16+n
        }
    }
    __syncthreads();

    // ---- phase 2: T1 = M @ Q (wave w: i in [w*32,w*32+32), c in [0,128)) --
    const int i0 = w * 32;
    floatx4 acc[2][8];
#pragma unroll
    for (int ti = 0; ti < 2; ti++)
#pragma unroll
        for (int tc = 0; tc < 8; tc++) acc[ti][tc] = z4;
#pragma unroll
    for (int k0 = 0; k0 < 256; k0 += 32) {
        const int k8 = k0 >> 3;
        bf16x8 a[2], b[8];
#pragma unroll
        for (int ti = 0; ti < 2; ti++)
            a[ti] = *(const bf16x8*)(Mb + (i0 + ti * 16 + n) * 256 + k0 + q * 8);
#pragma unroll
        for (int tc = 0; tc < 8; tc++)
            b[tc] = *(const bf16x8*)(smem + (tc * 16 + n) * 256 +
                                     (((k8 + q) ^ (n & 7)) << 3));
        __builtin_amdgcn_s_setprio(1);
#pragma unroll
        for (int ti = 0; ti < 2; ti++)
#pragma unroll
            for (int tc = 0; tc < 8; tc++)
                acc[ti][tc] = MFMA16(a[ti], b[tc], acc[ti][tc]);
        __builtin_amdgcn_s_setprio(0);
    }

    // ---- epilogue: in-register relu+Wg2 contraction + reduce-scatter ----
    // lane covers e = n (tc even) and e = 16+n (tc odd); bl = tc>>1 in 0..3.
    const float w2a = Wg2[n],      w2b = Wg2[16 + n];
    const float b1a = bg1[n],      b1b = bg1[16 + n];
    float v32[32];   // k = bl*8 + ti*4 + r
#pragma unroll
    for (int bl = 0; bl < 4; bl++)
#pragma unroll
        for (int ti = 0; ti < 2; ti++)
#pragma unroll
            for (int r = 0; r < 4; r++)
                v32[bl * 8 + ti * 4 + r] =
                    fmaxf(acc[ti][2 * bl][r] + b1a, 0.0f) * w2a +
                    fmaxf(acc[ti][2 * bl + 1][r] + b1b, 0.0f) * w2b;
    // reduce-scatter over lane bits 0..3; lane ends with k = n and k = 16+n.
    const bool h0 = (lane & 1), h1_ = (lane & 2), h2 = (lane & 4), h3 = (lane & 8);
    float u16[16];
#pragma unroll
    for (int p = 0; p < 16; p++) {
        const float keep = h0 ? v32[2 * p + 1] : v32[2 * p];
        const float send = h0 ? v32[2 * p] : v32[2 * p + 1];
        u16[p] = keep + __shfl_xor(send, 1, 64);
    }
    float u8[8];
#pragma unroll
    for (int p = 0; p < 8; p++) {
        const float keep = h1_ ? u16[2 * p + 1] : u16[2 * p];
        const float send = h1_ ? u16[2 * p] : u16[2 * p + 1];
        u8[p] = keep + __shfl_xor(send, 2, 64);
    }
    float u4[4];
#pragma unroll
    for (int p = 0; p < 4; p++) {
        const float keep = h2 ? u8[2 * p + 1] : u8[2 * p];
        const float send = h2 ? u8[2 * p] : u8[2 * p + 1];
        u4[p] = keep + __shfl_xor(send, 4, 64);
    }
    float u2[2];
#pragma unroll
    for (int p = 0; p < 2; p++) {
        const float keep = h3 ? u4[2 * p + 1] : u4[2 * p];
        const float send = h3 ? u4[2 * p] : u4[2 * p + 1];
        u2[p] = keep + __shfl_xor(send, 8, 64);
    }
    {
        // lane holds k = 16*p + n: r = n&3, ti = (n>>2)&1, bl = p*2 + (n>>3)
        const int i_out = i0 + ((n >> 2) & 1) * 16 + q * 4 + (n & 3);
        const int blv = n >> 3;
        Vout[bg * 1024 + blv * 256 + i_out] = u2[0];
        Vout[bg * 1024 + (2 + blv) * 256 + i_out] = u2[1];
    }
}

// ---------------------------------------------------------------------------
// K5: x_hat = V @ M^T + b_g2, in place.  256 blocks, 32-row bands.
// ---------------------------------------------------------------------------
__global__ __launch_bounds__(512) void k_out(
    float* __restrict__ VX, const bf16_t* __restrict__ Mb,
    const float* __restrict__ bg2) {
    __shared__ __align__(16) bf16_t va[32 * 264];
    const int tid = threadIdx.x;
    const int lane = tid & 63;
    const int w = tid >> 6;                 // wave 0..7 -> col group
    const int n = lane & 15, q = lane >> 4;
    const int r0 = blockIdx.x * 32;

#pragma unroll
    for (int p = 0; p < 4; p++) {
        const int i4 = p * 512 + tid;
        const int row = i4 >> 6, c4 = (i4 & 63) * 4;
        const floatx4 v = *(const floatx4*)(VX + (r0 + row) * 256 + c4);
        bf16x4 s;
#pragma unroll
        for (int r = 0; r < 4; r++) s[r] = (bf16_t)v[r];
        *(bf16x4*)(va + row * 264 + c4) = s;
    }
    __syncthreads();

    const int cw = w * 32;
    const floatx4 z4 = {0.f, 0.f, 0.f, 0.f};
    floatx4 acc[2][2];
#pragma unroll
    for (int rt = 0; rt < 2; rt++)
#pragma unroll
        for (int tc = 0; tc < 2; tc++) acc[rt][tc] = z4;
#pragma unroll 2
    for (int k0 = 0; k0 < 256; k0 += 32) {
        bf16x8 a[2], b[2];
#pragma unroll
        for (int rt = 0; rt < 2; rt++)
            a[rt] = *(const bf16x8*)(va + (rt * 16 + n) * 264 + k0 + q * 8);
#pragma unroll
        for (int tc = 0; tc < 2; tc++)
            b[tc] = *(const bf16x8*)(Mb + (cw + tc * 16 + n) * 256 + k0 + q * 8);
#pragma unroll
        for (int rt = 0; rt < 2; rt++)
#pragma unroll
            for (int tc = 0; tc < 2; tc++)
                acc[rt][tc] = MFMA16(a[rt], b[tc], acc[rt][tc]);
    }
    const float bv = bg2[0];
#pragma unroll
    for (int tc = 0; tc < 2; tc++) {
        const int col = cw + tc * 16 + n;
#pragma unroll
        for (int rt = 0; rt < 2; rt++)
#pragma unroll
            for (int r = 0; r < 4; r++)
                VX[(r0 + rt * 16 + q * 4 + r) * 256 + col] = acc[rt][tc][r] + bv;
    }
}

// ---------------------------------------------------------------------------
// K6: restore the real adjacency (fp32) — fallback path only (no d_ws).
// ---------------------------------------------------------------------------
__global__ __launch_bounds__(256) void k_adj(
    const float* __restrict__ gp, const int* __restrict__ iterp,
    float* __restrict__ adjOut) {
    const int o = blockIdx.x * 256 + threadIdx.x;  // o = j*256 + i
    const int j = o >> 8, i = o & 255;
    float g = 1.0f / (1.0f + expf(-gp[o]));
    if (i == j) g = 1.0f;
    if ((*iterp) > 50 && !(g > 0.1f)) g = 0.0f;
    adjOut[o] = g;
}

// ---------------------------------------------------------------------------
extern "C" void kernel_launch(void* const* d_in, const int* in_sizes, int n_in,
                              void* d_out, int out_size, void* d_ws, size_t ws_size,
                              hipStream_t stream) {
    const float* x    = (const float*)d_in[0];
    const float* eps  = (const float*)d_in[1];
    const float* Wenc = (const float*)d_in[2];
    const float* benc = (const float*)d_in[3];
    const float* Wmu  = (const float*)d_in[4];
    const float* bmu  = (const float*)d_in[5];
    const float* Wlv  = (const float*)d_in[6];
    const float* blv  = (const float*)d_in[7];
    const float* gp   = (const float*)d_in[8];
    const float* Wemb = (const float*)d_in[9];
    const float* bemb = (const float*)d_in[10];
    const float* Wg1  = (const float*)d_in[11];
    const float* bg1  = (const float*)d_in[12];
    const float* Wg2  = (const float*)d_in[13];
    const float* bg2  = (const float*)d_in[14];
    const int*   itr  = (const int*)d_in[15];
    (void)in_sizes; (void)n_in; (void)out_size;

    float* xhat = (float*)d_out;             // [8192,256] fp32
    float* adjO = xhat + ADJ_OFF;            // [256,256]  fp32
    float* muo  = xhat + MU_OFF;             // [8192,256] fp32
    float* lvo  = xhat + LV_OFF;             // [8192,256] fp32

    // Primary: scratch (Mb | wepack | bepack | colc | rsO, ~194 KB) in d_ws
    // -> adj slot is free from the start, k_mkM writes adjO, k_adj skipped.
    // Fallback (no/small d_ws): old layout in the adj slot + k_adj last.
    // Wt bf16 (384 KB) at xhat byte 4 MB: dead after k_ench (both paths).
    const bool usews = (d_ws != nullptr && ws_size >= 262144);
    char* scr = usews ? (char*)d_ws : (char*)adjO;
    bf16_t* Mb     = (bf16_t*)scr;
    bf16_t* wepack = (bf16_t*)(scr + 131072);
    bf16_t* bepack = (bf16_t*)(scr + 163840);
    int*    colc   = (int*)(scr + 196608);
    float*  rsO    = (float*)(scr + 197632);
    bf16_t* Wt     = (bf16_t*)((char*)d_out + 4194304);

    k_prep<<<dim3(208), dim3(256), 0, stream>>>(Wenc, Wmu, Wlv, Wemb, bemb,
                                                Wt, wepack, bepack, colc);
    k_deg <<<dim3(256), dim3(256), 0, stream>>>(gp, itr, colc, rsO);
    k_mkM <<<dim3(256), dim3(256), 0, stream>>>(gp, itr, colc, rsO, Mb,
                                                usews ? adjO : nullptr);
    k_ench<<<dim3(256), dim3(512), 0, stream>>>(x, Wt, benc, bmu, blv, muo, lvo);
    k_gcn <<<dim3(2048), dim3(512), 0, stream>>>(muo, lvo, eps, wepack, bepack,
                                                 Wg1, bg1, Wg2, Mb, xhat);
    k_out <<<dim3(256), dim3(512), 0, stream>>>(xhat, Mb, bg2);
    if (!usews)
        k_adj<<<dim3(256), dim3(256), 0, stream>>>(gp, itr, adjO);
}